// Round 9
// baseline (426.491 us; speedup 1.0000x reference)
//
#include <hip/hip_runtime.h>
#include <cstdint>
#include <cstddef>

#define E_DIM 512
#define H_DIM 512
#define V_DIM 32000
#define B_DIM 64
#define T_DIM 20
#define NBLK_LSTM 128

typedef _Float16 f16;
typedef _Float16 f16x8 __attribute__((ext_vector_type(8)));
typedef _Float16 f16x4 __attribute__((ext_vector_type(4)));
typedef float    f32x4 __attribute__((ext_vector_type(4)));

__device__ __forceinline__ void async_lds16(void* lds, const void* g) {
  __builtin_amdgcn_global_load_lds(
      (const __attribute__((address_space(1))) uint32_t*)g,
      (__attribute__((address_space(3))) uint32_t*)lds, 16, 0, 0);
}

__device__ __forceinline__ float sigmoidf_(float x) {
  return 1.0f / (1.0f + expf(-x));
}

// Agent-coherent (cross-XCD) 16B load of h: two relaxed 8B atomic loads that
// bypass the non-coherent per-XCD L2s (read at the coherence point).
__device__ __forceinline__ f16x8 load_h8_coh(const f16* p) {
  union { unsigned long long u[2]; f16x8 v; } r;
  r.u[0] = __hip_atomic_load((const unsigned long long*)p,
                             __ATOMIC_RELAXED, __HIP_MEMORY_SCOPE_AGENT);
  r.u[1] = __hip_atomic_load((const unsigned long long*)(p + 4),
                             __ATOMIC_RELAXED, __HIP_MEMORY_SCOPE_AGENT);
  return r.v;
}
__device__ __forceinline__ void store_h_coh(f16* p, float v) {
  union { f16 h; unsigned short s; } cvt;
  cvt.h = (f16)v;
  __hip_atomic_store((unsigned short*)p, cvt.s,
                     __ATOMIC_RELAXED, __HIP_MEMORY_SCOPE_AGENT);
}

// ---------------------------------------------------------------------------
// Gather x rows to fp16, T-MAJOR: x16[m'][512], m' = t*64 + b (t<21, b<64);
// rows 1344..1407 zero pad. Step t's P rows are then contiguous (512 KB).
// ---------------------------------------------------------------------------
__global__ __launch_bounds__(128) void gather_x16_kernel(
    const float* __restrict__ features, const int* __restrict__ captions,
    const float* __restrict__ emb, f16* __restrict__ x16) {
  const int m = blockIdx.x;
  const int j = threadIdx.x;
  f16x4 r4 = {(f16)0.f, (f16)0.f, (f16)0.f, (f16)0.f};
  if (m < 1344) {
    const int b = m & 63;
    const int t = m >> 6;
    const float* src = (t == 0)
        ? features + (size_t)b * E_DIM
        : emb + (size_t)captions[b * T_DIM + (t - 1)] * E_DIM;
    const float4 v = ((const float4*)src)[j];
    r4.x = (f16)v.x; r4.y = (f16)v.y; r4.z = (f16)v.z; r4.w = (f16)v.w;
  }
  ((f16x4*)(x16 + (size_t)m * 512))[j] = r4;
}

__global__ __launch_bounds__(256) void convert_w_kernel(
    const float* __restrict__ w, f16* __restrict__ w16) {
  const int i = blockIdx.x * 256 + threadIdx.x;
  const float4 v = ((const float4*)w)[i];
  f16x4 r;
  r.x = (f16)v.x; r.y = (f16)v.y; r.z = (f16)v.z; r.w = (f16)v.w;
  ((f16x4*)w16)[i] = r;
}

__global__ __launch_bounds__(256) void bias_sum_kernel(
    const float* __restrict__ a, const float* __restrict__ b,
    float* __restrict__ o) {
  const int i = blockIdx.x * 256 + threadIdx.x;
  if (i < 2048) o[i] = a[i] + b[i];
}

// ---------------------------------------------------------------------------
// K=512 fp16 GEMM (B^T form): C = A.Bw^T + bias. 128x128 tile, BK=64,
// 4 waves (2x2), 16x16x32 f16 MFMA, global_load_lds. f32-C variant.
// ---------------------------------------------------------------------------
__global__ __launch_bounds__(256) void gemm16_kernel(
    const f16* __restrict__ A, const f16* __restrict__ Bw,
    const float* __restrict__ bias, float* __restrict__ C, int ldc) {
  __shared__ f16 As[128 * 64];
  __shared__ f16 Bs[128 * 64];
  const int tid = threadIdx.x;
  const int lane = tid & 63;
  const int wid = tid >> 6;
  const int m0 = blockIdx.y * 128;
  const int n0 = blockIdx.x * 128;
  const int wm = (wid >> 1) * 64;
  const int wn = (wid & 1) * 64;

  f32x4 acc[4][4];
#pragma unroll
  for (int i = 0; i < 4; ++i)
#pragma unroll
    for (int j = 0; j < 4; ++j) {
      f32x4 z = {0.f, 0.f, 0.f, 0.f};
      acc[i][j] = z;
    }
  const int lr = lane & 15;
  const int lkb = (lane >> 4) * 8;

  for (int kt = 0; kt < 512; kt += 64) {
#pragma unroll
    for (int i = 0; i < 4; ++i) {
      const int off = i * 4096 + wid * 1024 + lane * 16;
      const int row = off >> 7;
      const int colh = (off & 127) >> 1;
      async_lds16((char*)As + i * 4096 + wid * 1024,
                  A + (size_t)(m0 + row) * 512 + kt + colh);
      async_lds16((char*)Bs + i * 4096 + wid * 1024,
                  Bw + (size_t)(n0 + row) * 512 + kt + colh);
    }
    __syncthreads();
#pragma unroll
    for (int ks = 0; ks < 2; ++ks) {
      f16x8 af[4], bf[4];
#pragma unroll
      for (int mi = 0; mi < 4; ++mi)
        af[mi] = *(const f16x8*)&As[(wm + mi * 16 + lr) * 64 + ks * 32 + lkb];
#pragma unroll
      for (int ni = 0; ni < 4; ++ni)
        bf[ni] = *(const f16x8*)&Bs[(wn + ni * 16 + lr) * 64 + ks * 32 + lkb];
#pragma unroll
      for (int mi = 0; mi < 4; ++mi)
#pragma unroll
        for (int ni = 0; ni < 4; ++ni)
          acc[mi][ni] = __builtin_amdgcn_mfma_f32_16x16x32_f16(
              af[mi], bf[ni], acc[mi][ni], 0, 0, 0);
    }
    __syncthreads();
  }

#pragma unroll
  for (int mi = 0; mi < 4; ++mi) {
    const int mbase = m0 + wm + mi * 16 + (lane >> 4) * 4;
#pragma unroll
    for (int ni = 0; ni < 4; ++ni) {
      const int n = n0 + wn + ni * 16 + lr;
      const float bv = bias[n];
#pragma unroll
      for (int r = 0; r < 4; ++r)
        C[(size_t)(mbase + r) * ldc + n] = acc[mi][ni][r] + bv;
    }
  }
}

// Same GEMM, f16 C output (halves logit-write traffic). ldc fixed 32000.
__global__ __launch_bounds__(256) void gemm16_f16out_kernel(
    const f16* __restrict__ A, const f16* __restrict__ Bw,
    const float* __restrict__ bias, f16* __restrict__ C16) {
  __shared__ f16 As[128 * 64];
  __shared__ f16 Bs[128 * 64];
  const int tid = threadIdx.x;
  const int lane = tid & 63;
  const int wid = tid >> 6;
  const int m0 = blockIdx.y * 128;
  const int n0 = blockIdx.x * 128;
  const int wm = (wid >> 1) * 64;
  const int wn = (wid & 1) * 64;

  f32x4 acc[4][4];
#pragma unroll
  for (int i = 0; i < 4; ++i)
#pragma unroll
    for (int j = 0; j < 4; ++j) {
      f32x4 z = {0.f, 0.f, 0.f, 0.f};
      acc[i][j] = z;
    }
  const int lr = lane & 15;
  const int lkb = (lane >> 4) * 8;

  for (int kt = 0; kt < 512; kt += 64) {
#pragma unroll
    for (int i = 0; i < 4; ++i) {
      const int off = i * 4096 + wid * 1024 + lane * 16;
      const int row = off >> 7;
      const int colh = (off & 127) >> 1;
      async_lds16((char*)As + i * 4096 + wid * 1024,
                  A + (size_t)(m0 + row) * 512 + kt + colh);
      async_lds16((char*)Bs + i * 4096 + wid * 1024,
                  Bw + (size_t)(n0 + row) * 512 + kt + colh);
    }
    __syncthreads();
#pragma unroll
    for (int ks = 0; ks < 2; ++ks) {
      f16x8 af[4], bf[4];
#pragma unroll
      for (int mi = 0; mi < 4; ++mi)
        af[mi] = *(const f16x8*)&As[(wm + mi * 16 + lr) * 64 + ks * 32 + lkb];
#pragma unroll
      for (int ni = 0; ni < 4; ++ni)
        bf[ni] = *(const f16x8*)&Bs[(wn + ni * 16 + lr) * 64 + ks * 32 + lkb];
#pragma unroll
      for (int mi = 0; mi < 4; ++mi)
#pragma unroll
        for (int ni = 0; ni < 4; ++ni)
          acc[mi][ni] = __builtin_amdgcn_mfma_f32_16x16x32_f16(
              af[mi], bf[ni], acc[mi][ni], 0, 0, 0);
    }
    __syncthreads();
  }

#pragma unroll
  for (int mi = 0; mi < 4; ++mi) {
    const int mbase = m0 + wm + mi * 16 + (lane >> 4) * 4;
#pragma unroll
    for (int ni = 0; ni < 4; ++ni) {
      const int n = n0 + wn + ni * 16 + lr;
      const float bv = bias[n];
#pragma unroll
      for (int r = 0; r < 4; ++r)
        C16[(size_t)(mbase + r) * 32000 + n] = (f16)(acc[mi][ni][r] + bv);
    }
  }
}

// ---------------------------------------------------------------------------
// Persistent LSTM v2: 21 steps in ONE kernel, NO cache-flush fences.
// h exchange via agent-scope RELAXED atomics (coherence-point access, bypasses
// the non-coherent per-XCD L2s); barrier = vmcnt(0) drain + relaxed counter.
// w_hh/P are read-only in-kernel -> normal cacheable loads, L2-hot across
// steps (the r7 fence approach killed exactly this reuse).
// 128 blocks x 256 thr, 0 LDS -> co-resident on 256 CUs. c in registers.
// Layout identical to lstm_step_direct (r8): block u0=blk*4; wave = 16 b-rows;
// gate-row = lane&15; gates i,f,g,o at lanes fr, fr^4, fr^8, fr^12.
// P is t-major: row = t*64 + b.
// ---------------------------------------------------------------------------
__global__ __launch_bounds__(256) void lstm_persistent2(
    const float* __restrict__ P, const f16* __restrict__ Whh,
    f16* __restrict__ hA, f16* __restrict__ hB,
    f16* __restrict__ hs16, unsigned* __restrict__ bar) {
  const int tid = threadIdx.x;
  const int lane = tid & 63;
  const int w = tid >> 6;
  const int u0 = blockIdx.x * 4;
  const int fr = lane & 15;
  const int fq = lane >> 4;
  const int grow = (fr >> 2) * 512 + u0 + (fr & 3);
  const f16* brow = Whh + (size_t)grow * 512;  // w_hh row, cached, reused 20x

  float cr[4] = {0.f, 0.f, 0.f, 0.f};  // c for (b = w*16+fq*4+r, u = u0+fr)

  for (int t = 0; t <= T_DIM; ++t) {
    f32x4 acc = {0.f, 0.f, 0.f, 0.f};
    if (t > 0) {
      const f16* hin = (t & 1) ? hA : hB;
      const f16* arow = hin + (size_t)(w * 16 + fr) * 512;
      f16x8 a[16], b[16];
#pragma unroll
      for (int kk = 0; kk < 16; ++kk) {
        const int kc = kk * 32 + fq * 8;
        a[kk] = load_h8_coh(&arow[kc]);
        b[kk] = *(const f16x8*)&brow[kc];
      }
#pragma unroll
      for (int kk = 0; kk < 16; ++kk)
        acc = __builtin_amdgcn_mfma_f32_16x16x32_f16(a[kk], b[kk], acc,
                                                     0, 0, 0);
    }
    // add input projection + biases; P row = t*64 + b (t-major)
#pragma unroll
    for (int r = 0; r < 4; ++r) {
      const int b = w * 16 + fq * 4 + r;
      acc[r] += P[((size_t)(t * 64 + b)) * 2048 + grow];
    }

    f16* hout = (t & 1) ? hB : hA;
#pragma unroll
    for (int r = 0; r < 4; ++r) {
      const float x  = acc[r];
      const float xf = __shfl_xor(x, 4);
      const float xg = __shfl_xor(x, 8);
      const float xo = __shfl_xor(x, 12);
      if (fr < 4) {
        const int b = w * 16 + fq * 4 + r;
        const int u = u0 + fr;
        const float si = sigmoidf_(x);
        const float sf = sigmoidf_(xf);
        const float tg = tanhf(xg);
        const float so = sigmoidf_(xo);
        const float cn = sf * cr[r] + si * tg;
        cr[r] = cn;
        const float hn = so * tanhf(cn);
        store_h_coh(&hout[(size_t)b * 512 + u], hn);
        if (t >= 1)
          hs16[((size_t)b * T_DIM + (t - 1)) * 512 + u] = (f16)hn;
      }
    }

    if (t < T_DIM) {
      // drain own coherent stores to the coherence point, then count in.
      asm volatile("s_waitcnt vmcnt(0)" ::: "memory");
      __syncthreads();
      if (tid == 0) {
        __hip_atomic_fetch_add(bar, 1u, __ATOMIC_RELAXED,
                               __HIP_MEMORY_SCOPE_AGENT);
        const unsigned target = (unsigned)(NBLK_LSTM * (t + 1));
        while (__hip_atomic_load(bar, __ATOMIC_RELAXED,
                                 __HIP_MEMORY_SCOPE_AGENT) < target)
          __builtin_amdgcn_s_sleep(1);
      }
      __syncthreads();
    }
  }
}

// ---------------------------------------------------------------------------
// Softmax over V=32000, row in registers (1024 thr). f16-logit input variant
// and f32 in-place fallback.
// ---------------------------------------------------------------------------
__device__ __forceinline__ float waveMax(float v) {
#pragma unroll
  for (int o = 32; o > 0; o >>= 1) v = fmaxf(v, __shfl_down(v, o));
  return v;
}
__device__ __forceinline__ float waveSum(float v) {
#pragma unroll
  for (int o = 32; o > 0; o >>= 1) v += __shfl_down(v, o);
  return v;
}

__global__ __launch_bounds__(1024) void softmax_f16_kernel(
    const f16* __restrict__ lg, float* __restrict__ out) {
  const f16x8* L = (const f16x8*)(lg + (size_t)blockIdx.x * V_DIM);
  float4* p4 = (float4*)(out + (size_t)blockIdx.x * V_DIM);
  const int t = threadIdx.x;
  __shared__ float sred[16];

  float4 v[8];
  float m = -1e30f;
#pragma unroll
  for (int j = 0; j < 4; ++j) {
    const int i = j * 1024 + t;        // f16x8 index, < 4000
    if (i < 4000) {
      const f16x8 h = L[i];
      v[2 * j].x     = (float)h[0]; v[2 * j].y     = (float)h[1];
      v[2 * j].z     = (float)h[2]; v[2 * j].w     = (float)h[3];
      v[2 * j + 1].x = (float)h[4]; v[2 * j + 1].y = (float)h[5];
      v[2 * j + 1].z = (float)h[6]; v[2 * j + 1].w = (float)h[7];
      m = fmaxf(m, fmaxf(fmaxf(v[2 * j].x, v[2 * j].y),
                         fmaxf(v[2 * j].z, v[2 * j].w)));
      m = fmaxf(m, fmaxf(fmaxf(v[2 * j + 1].x, v[2 * j + 1].y),
                         fmaxf(v[2 * j + 1].z, v[2 * j + 1].w)));
    }
  }
  m = waveMax(m);
  if ((t & 63) == 0) sred[t >> 6] = m;
  __syncthreads();
  float mb = sred[0];
#pragma unroll
  for (int k = 1; k < 16; ++k) mb = fmaxf(mb, sred[k]);
  __syncthreads();

  float s = 0.f;
#pragma unroll
  for (int j = 0; j < 8; ++j) {
    const int i = (j >> 1) * 1024 + t;
    if (i < 4000) {
      v[j].x = expf(v[j].x - mb);
      v[j].y = expf(v[j].y - mb);
      v[j].z = expf(v[j].z - mb);
      v[j].w = expf(v[j].w - mb);
      s += v[j].x + v[j].y + v[j].z + v[j].w;
    }
  }
  s = waveSum(s);
  if ((t & 63) == 0) sred[t >> 6] = s;
  __syncthreads();
  float sb = sred[0];
#pragma unroll
  for (int k = 1; k < 16; ++k) sb += sred[k];
  const float inv = 1.0f / sb;

#pragma unroll
  for (int j = 0; j < 4; ++j) {
    const int i = j * 1024 + t;
    if (i < 4000) {
      float4 a = v[2 * j], b = v[2 * j + 1];
      a.x *= inv; a.y *= inv; a.z *= inv; a.w *= inv;
      b.x *= inv; b.y *= inv; b.z *= inv; b.w *= inv;
      p4[2 * i] = a;
      p4[2 * i + 1] = b;
    }
  }
}

__global__ __launch_bounds__(1024) void softmax_reg_kernel(
    float* __restrict__ out) {
  float4* p4 = (float4*)(out + (size_t)blockIdx.x * V_DIM);
  const int t = threadIdx.x;
  __shared__ float sred[16];
  float4 v[8];
  float m = -1e30f;
#pragma unroll
  for (int j = 0; j < 8; ++j) {
    const int i = j * 1024 + t;
    if (i < 8000) {
      v[j] = p4[i];
      m = fmaxf(m, fmaxf(fmaxf(v[j].x, v[j].y), fmaxf(v[j].z, v[j].w)));
    }
  }
  m = waveMax(m);
  if ((t & 63) == 0) sred[t >> 6] = m;
  __syncthreads();
  float mb = sred[0];
#pragma unroll
  for (int k = 1; k < 16; ++k) mb = fmaxf(mb, sred[k]);
  __syncthreads();
  float s = 0.f;
#pragma unroll
  for (int j = 0; j < 8; ++j) {
    const int i = j * 1024 + t;
    if (i < 8000) {
      v[j].x = expf(v[j].x - mb);
      v[j].y = expf(v[j].y - mb);
      v[j].z = expf(v[j].z - mb);
      v[j].w = expf(v[j].w - mb);
      s += v[j].x + v[j].y + v[j].z + v[j].w;
    }
  }
  s = waveSum(s);
  if ((t & 63) == 0) sred[t >> 6] = s;
  __syncthreads();
  float sb = sred[0];
#pragma unroll
  for (int k = 1; k < 16; ++k) sb += sred[k];
  const float inv = 1.0f / sb;
#pragma unroll
  for (int j = 0; j < 8; ++j) {
    const int i = j * 1024 + t;
    if (i < 8000) {
      float4 o;
      o.x = v[j].x * inv; o.y = v[j].y * inv;
      o.z = v[j].z * inv; o.w = v[j].w * inv;
      p4[i] = o;
    }
  }
}

// ---------------------------------------------------------------------------
extern "C" void kernel_launch(void* const* d_in, const int* in_sizes, int n_in,
                              void* d_out, int out_size, void* d_ws, size_t ws_size,
                              hipStream_t stream) {
  const float* features = (const float*)d_in[0];
  const int*   captions = (const int*)d_in[1];
  const float* emb      = (const float*)d_in[3];
  const float* w_ih     = (const float*)d_in[4];
  const float* w_hh     = (const float*)d_in[5];
  const float* b_ih     = (const float*)d_in[6];
  const float* b_hh     = (const float*)d_in[7];
  const float* fc_w     = (const float*)d_in[8];
  const float* fc_b     = (const float*)d_in[9];
  float* out = (float*)d_out;

  // ---- d_ws layout ----
  char* ws = (char*)d_ws;
  unsigned* bar = (unsigned*)ws; ws += 256;
  f16*   h16a = (f16*)ws;   ws += (size_t)B_DIM * H_DIM * 2;            // 64 KB
  f16*   h16b = (f16*)ws;   ws += (size_t)B_DIM * H_DIM * 2;            // 64 KB
  f16*   hs16 = (f16*)ws;   ws += (size_t)B_DIM * T_DIM * H_DIM * 2;    // 1.31 MB
  f16*   w16  = (f16*)ws;   ws += (size_t)V_DIM * H_DIM * 2;            // 32.77 MB
  f16*   logits16 = (f16*)ws;  // 81.92 MB if available
  const size_t ws_need_f16logits =
      ((char*)logits16 - (char*)d_ws) + (size_t)1280 * V_DIM * 2;  // ~116 MB
  const bool use_f16_logits = ws_size >= ws_need_f16logits;

  // ---- transient scratch in d_out (dead before final output writes) ----
  float* P     = out;                          // [1408][2048] f32, 11.5 MB
  f16*   x16   = (f16*)(out + 3000000);        // [1408][512] f16
  f16*   wih16 = (f16*)(out + 3400000);        // [2048][512] f16
  f16*   whh16 = (f16*)(out + 4000000);        // [2048][512] f16
  float* bsum  = out + 4600000;                // [2048] f32

  hipMemsetAsync(bar, 0, 256, stream);

  gather_x16_kernel<<<1408, 128, 0, stream>>>(features, captions, emb, x16);
  convert_w_kernel<<<1024, 256, 0, stream>>>(w_ih, wih16);
  convert_w_kernel<<<1024, 256, 0, stream>>>(w_hh, whh16);
  convert_w_kernel<<<16000, 256, 0, stream>>>(fc_w, w16);
  bias_sum_kernel<<<8, 256, 0, stream>>>(b_ih, b_hh, bsum);

  // proj: P[1408][2048] = x16 @ wih16^T + bsum   (rows t-major: m' = t*64+b)
  gemm16_kernel<<<dim3(16, 11), 256, 0, stream>>>(x16, wih16, bsum, P, 2048);

  // all 21 LSTM steps, one kernel, fence-free coherent h exchange
  lstm_persistent2<<<NBLK_LSTM, 256, 0, stream>>>(P, whh16, h16a, h16b,
                                                  hs16, bar);

  if (use_f16_logits) {
    gemm16_f16out_kernel<<<dim3(250, 10), 256, 0, stream>>>(hs16, w16, fc_b,
                                                            logits16);
    softmax_f16_kernel<<<1280, 1024, 0, stream>>>(logits16, out);
  } else {
    gemm16_kernel<<<dim3(250, 10), 256, 0, stream>>>(hs16, w16, fc_b, out,
                                                     32000);
    softmax_reg_kernel<<<1280, 1024, 0, stream>>>(out);
  }
}

// Round 10
// 419.106 us; speedup vs baseline: 1.0176x; 1.0176x over previous
//
#include <hip/hip_runtime.h>
#include <cstdint>
#include <cstddef>

#define E_DIM 512
#define H_DIM 512
#define V_DIM 32000
#define B_DIM 64
#define T_DIM 20
#define NBLK_LSTM 128

typedef _Float16 f16;
typedef _Float16 f16x8 __attribute__((ext_vector_type(8)));
typedef _Float16 f16x4 __attribute__((ext_vector_type(4)));
typedef float    f32x4 __attribute__((ext_vector_type(4)));

__device__ __forceinline__ void async_lds16(void* lds, const void* g) {
  __builtin_amdgcn_global_load_lds(
      (const __attribute__((address_space(1))) uint32_t*)g,
      (__attribute__((address_space(3))) uint32_t*)lds, 16, 0, 0);
}

__device__ __forceinline__ float sigmoidf_(float x) {
  return 1.0f / (1.0f + expf(-x));
}

// Agent-coherent (cross-XCD) accesses: relaxed atomics bypass the
// non-coherent per-XCD L2s and hit the coherence point (LLC).
__device__ __forceinline__ f16x8 load_h8_coh(const f16* p) {
  union { unsigned long long u[2]; f16x8 v; } r;
  r.u[0] = __hip_atomic_load((const unsigned long long*)p,
                             __ATOMIC_RELAXED, __HIP_MEMORY_SCOPE_AGENT);
  r.u[1] = __hip_atomic_load((const unsigned long long*)(p + 4),
                             __ATOMIC_RELAXED, __HIP_MEMORY_SCOPE_AGENT);
  return r.v;
}
__device__ __forceinline__ void store_h_coh(f16* p, float v) {
  union { f16 h; unsigned short s; } cvt;
  cvt.h = (f16)v;
  __hip_atomic_store((unsigned short*)p, cvt.s,
                     __ATOMIC_RELAXED, __HIP_MEMORY_SCOPE_AGENT);
}

// ---------------------------------------------------------------------------
// Gather x rows to fp16, T-MAJOR: x16[m'][512], m' = t*64 + b; rows
// 1344..1407 zero pad. Step t's P rows are then one contiguous 512KB slab.
// ---------------------------------------------------------------------------
__global__ __launch_bounds__(128) void gather_x16_kernel(
    const float* __restrict__ features, const int* __restrict__ captions,
    const float* __restrict__ emb, f16* __restrict__ x16) {
  const int m = blockIdx.x;
  const int j = threadIdx.x;
  f16x4 r4 = {(f16)0.f, (f16)0.f, (f16)0.f, (f16)0.f};
  if (m < 1344) {
    const int b = m & 63;
    const int t = m >> 6;
    const float* src = (t == 0)
        ? features + (size_t)b * E_DIM
        : emb + (size_t)captions[b * T_DIM + (t - 1)] * E_DIM;
    const float4 v = ((const float4*)src)[j];
    r4.x = (f16)v.x; r4.y = (f16)v.y; r4.z = (f16)v.z; r4.w = (f16)v.w;
  }
  ((f16x4*)(x16 + (size_t)m * 512))[j] = r4;
}

__global__ __launch_bounds__(256) void convert_w_kernel(
    const float* __restrict__ w, f16* __restrict__ w16) {
  const int i = blockIdx.x * 256 + threadIdx.x;
  const float4 v = ((const float4*)w)[i];
  f16x4 r;
  r.x = (f16)v.x; r.y = (f16)v.y; r.z = (f16)v.z; r.w = (f16)v.w;
  ((f16x4*)w16)[i] = r;
}

__global__ __launch_bounds__(256) void bias_sum_kernel(
    const float* __restrict__ a, const float* __restrict__ b,
    float* __restrict__ o) {
  const int i = blockIdx.x * 256 + threadIdx.x;
  if (i < 2048) o[i] = a[i] + b[i];
}

// ---------------------------------------------------------------------------
// K=512 fp16 GEMM (B^T form): C = A.Bw^T + bias. 128x128 tile, BK=64,
// 4 waves (2x2), 16x16x32 f16 MFMA, global_load_lds.
// remap!=0: A rows are (t*64+b)-ordered; C row = (r&63)*20 + (r>>6).
// ---------------------------------------------------------------------------
__global__ __launch_bounds__(256) void gemm16_kernel(
    const f16* __restrict__ A, const f16* __restrict__ Bw,
    const float* __restrict__ bias, float* __restrict__ C, int ldc,
    int remap) {
  __shared__ f16 As[128 * 64];
  __shared__ f16 Bs[128 * 64];
  const int tid = threadIdx.x;
  const int lane = tid & 63;
  const int wid = tid >> 6;
  const int m0 = blockIdx.y * 128;
  const int n0 = blockIdx.x * 128;
  const int wm = (wid >> 1) * 64;
  const int wn = (wid & 1) * 64;

  f32x4 acc[4][4];
#pragma unroll
  for (int i = 0; i < 4; ++i)
#pragma unroll
    for (int j = 0; j < 4; ++j) {
      f32x4 z = {0.f, 0.f, 0.f, 0.f};
      acc[i][j] = z;
    }
  const int lr = lane & 15;
  const int lkb = (lane >> 4) * 8;

  for (int kt = 0; kt < 512; kt += 64) {
#pragma unroll
    for (int i = 0; i < 4; ++i) {
      const int off = i * 4096 + wid * 1024 + lane * 16;
      const int row = off >> 7;
      const int colh = (off & 127) >> 1;
      async_lds16((char*)As + i * 4096 + wid * 1024,
                  A + (size_t)(m0 + row) * 512 + kt + colh);
      async_lds16((char*)Bs + i * 4096 + wid * 1024,
                  Bw + (size_t)(n0 + row) * 512 + kt + colh);
    }
    __syncthreads();
#pragma unroll
    for (int ks = 0; ks < 2; ++ks) {
      f16x8 af[4], bf[4];
#pragma unroll
      for (int mi = 0; mi < 4; ++mi)
        af[mi] = *(const f16x8*)&As[(wm + mi * 16 + lr) * 64 + ks * 32 + lkb];
#pragma unroll
      for (int ni = 0; ni < 4; ++ni)
        bf[ni] = *(const f16x8*)&Bs[(wn + ni * 16 + lr) * 64 + ks * 32 + lkb];
#pragma unroll
      for (int mi = 0; mi < 4; ++mi)
#pragma unroll
        for (int ni = 0; ni < 4; ++ni)
          acc[mi][ni] = __builtin_amdgcn_mfma_f32_16x16x32_f16(
              af[mi], bf[ni], acc[mi][ni], 0, 0, 0);
    }
    __syncthreads();
  }

#pragma unroll
  for (int mi = 0; mi < 4; ++mi) {
    const int mbase = m0 + wm + mi * 16 + (lane >> 4) * 4;
#pragma unroll
    for (int ni = 0; ni < 4; ++ni) {
      const int n = n0 + wn + ni * 16 + lr;
      const float bv = bias[n];
#pragma unroll
      for (int r = 0; r < 4; ++r) {
        const int mr = mbase + r;
        const int orow = remap ? ((mr & 63) * 20 + (mr >> 6)) : mr;
        C[(size_t)orow * ldc + n] = acc[mi][ni][r] + bv;
      }
    }
  }
}

// Same GEMM, f16 C output, FC-only (ldc=32000, always remapped rows).
__global__ __launch_bounds__(256) void gemm16_f16out_kernel(
    const f16* __restrict__ A, const f16* __restrict__ Bw,
    const float* __restrict__ bias, f16* __restrict__ C16) {
  __shared__ f16 As[128 * 64];
  __shared__ f16 Bs[128 * 64];
  const int tid = threadIdx.x;
  const int lane = tid & 63;
  const int wid = tid >> 6;
  const int m0 = blockIdx.y * 128;
  const int n0 = blockIdx.x * 128;
  const int wm = (wid >> 1) * 64;
  const int wn = (wid & 1) * 64;

  f32x4 acc[4][4];
#pragma unroll
  for (int i = 0; i < 4; ++i)
#pragma unroll
    for (int j = 0; j < 4; ++j) {
      f32x4 z = {0.f, 0.f, 0.f, 0.f};
      acc[i][j] = z;
    }
  const int lr = lane & 15;
  const int lkb = (lane >> 4) * 8;

  for (int kt = 0; kt < 512; kt += 64) {
#pragma unroll
    for (int i = 0; i < 4; ++i) {
      const int off = i * 4096 + wid * 1024 + lane * 16;
      const int row = off >> 7;
      const int colh = (off & 127) >> 1;
      async_lds16((char*)As + i * 4096 + wid * 1024,
                  A + (size_t)(m0 + row) * 512 + kt + colh);
      async_lds16((char*)Bs + i * 4096 + wid * 1024,
                  Bw + (size_t)(n0 + row) * 512 + kt + colh);
    }
    __syncthreads();
#pragma unroll
    for (int ks = 0; ks < 2; ++ks) {
      f16x8 af[4], bf[4];
#pragma unroll
      for (int mi = 0; mi < 4; ++mi)
        af[mi] = *(const f16x8*)&As[(wm + mi * 16 + lr) * 64 + ks * 32 + lkb];
#pragma unroll
      for (int ni = 0; ni < 4; ++ni)
        bf[ni] = *(const f16x8*)&Bs[(wn + ni * 16 + lr) * 64 + ks * 32 + lkb];
#pragma unroll
      for (int mi = 0; mi < 4; ++mi)
#pragma unroll
        for (int ni = 0; ni < 4; ++ni)
          acc[mi][ni] = __builtin_amdgcn_mfma_f32_16x16x32_f16(
              af[mi], bf[ni], acc[mi][ni], 0, 0, 0);
    }
    __syncthreads();
  }

#pragma unroll
  for (int mi = 0; mi < 4; ++mi) {
    const int mbase = m0 + wm + mi * 16 + (lane >> 4) * 4;
#pragma unroll
    for (int ni = 0; ni < 4; ++ni) {
      const int n = n0 + wn + ni * 16 + lr;
      const float bv = bias[n];
#pragma unroll
      for (int r = 0; r < 4; ++r) {
        const int mr = mbase + r;
        const int orow = (mr & 63) * 20 + (mr >> 6);
        C16[(size_t)orow * 32000 + n] = (f16)(acc[mi][ni][r] + bv);
      }
    }
  }
}

// ---------------------------------------------------------------------------
// Persistent LSTM v3: 21 steps, ONE kernel. Sync = contention-free flag-array
// barrier (block j stores step# to flags[j]; threads 0..127 poll one flag
// each in parallel). h lives directly in t-major hsT slabs [21][64][512]
// (step t writes slab t, reads slab t-1) via agent-coherent relaxed atomics.
// w_hh slice (16KB/block) and P stay normal cached loads -> L2-hot across
// steps. 128 blocks x 256 thr, 0 LDS, c in registers. t=0 skips MFMA.
// ---------------------------------------------------------------------------
__global__ __launch_bounds__(256) void lstm_persistent3(
    const float* __restrict__ P, const f16* __restrict__ Whh,
    f16* __restrict__ hsT, unsigned* __restrict__ flags) {
  const int tid = threadIdx.x;
  const int lane = tid & 63;
  const int w = tid >> 6;
  const int u0 = blockIdx.x * 4;
  const int fr = lane & 15;
  const int fq = lane >> 4;
  const int grow = (fr >> 2) * 512 + u0 + (fr & 3);
  const f16* brow = Whh + (size_t)grow * 512;  // L2-hot across all steps

  float cr[4] = {0.f, 0.f, 0.f, 0.f};  // c for (b = w*16+fq*4+r, u = u0+fr)

  for (int t = 0; t <= T_DIM; ++t) {
    f32x4 acc = {0.f, 0.f, 0.f, 0.f};
    if (t > 0) {
      const f16* arow = hsT + (size_t)(t - 1) * (64 * 512)
                            + (size_t)(w * 16 + fr) * 512;
      f16x8 a[16], b[16];
#pragma unroll
      for (int kk = 0; kk < 16; ++kk) {
        const int kc = kk * 32 + fq * 8;
        a[kk] = load_h8_coh(&arow[kc]);
        b[kk] = *(const f16x8*)&brow[kc];
      }
#pragma unroll
      for (int kk = 0; kk < 16; ++kk)
        acc = __builtin_amdgcn_mfma_f32_16x16x32_f16(a[kk], b[kk], acc,
                                                     0, 0, 0);
    }
    // add input projection + biases; P row = t*64 + b (t-major)
#pragma unroll
    for (int r = 0; r < 4; ++r) {
      const int b = w * 16 + fq * 4 + r;
      acc[r] += P[((size_t)(t * 64 + b)) * 2048 + grow];
    }

    f16* hout = hsT + (size_t)t * (64 * 512);
#pragma unroll
    for (int r = 0; r < 4; ++r) {
      const float x  = acc[r];
      const float xf = __shfl_xor(x, 4);
      const float xg = __shfl_xor(x, 8);
      const float xo = __shfl_xor(x, 12);
      if (fr < 4) {
        const int b = w * 16 + fq * 4 + r;
        const int u = u0 + fr;
        const float si = sigmoidf_(x);
        const float sf = sigmoidf_(xf);
        const float tg = tanhf(xg);
        const float so = sigmoidf_(xo);
        const float cn = sf * cr[r] + si * tg;
        cr[r] = cn;
        const float hn = so * tanhf(cn);
        store_h_coh(&hout[(size_t)b * 512 + u], hn);
      }
    }

    if (t < T_DIM) {
      // drain own coherent stores (per-wave), then flag-array barrier.
      asm volatile("s_waitcnt vmcnt(0)" ::: "memory");
      __syncthreads();
      if (tid == 0)
        __hip_atomic_store(&flags[blockIdx.x], (unsigned)(t + 1),
                           __ATOMIC_RELAXED, __HIP_MEMORY_SCOPE_AGENT);
      if (tid < NBLK_LSTM) {
        while (__hip_atomic_load(&flags[tid], __ATOMIC_RELAXED,
                                 __HIP_MEMORY_SCOPE_AGENT) < (unsigned)(t + 1))
          __builtin_amdgcn_s_sleep(2);
      }
      __syncthreads();
    }
  }
}

// ---------------------------------------------------------------------------
// Softmax over V=32000, row in registers (1024 thr). f16-logit input variant
// and f32 in-place fallback.
// ---------------------------------------------------------------------------
__device__ __forceinline__ float waveMax(float v) {
#pragma unroll
  for (int o = 32; o > 0; o >>= 1) v = fmaxf(v, __shfl_down(v, o));
  return v;
}
__device__ __forceinline__ float waveSum(float v) {
#pragma unroll
  for (int o = 32; o > 0; o >>= 1) v += __shfl_down(v, o);
  return v;
}

__global__ __launch_bounds__(1024) void softmax_f16_kernel(
    const f16* __restrict__ lg, float* __restrict__ out) {
  const f16x8* L = (const f16x8*)(lg + (size_t)blockIdx.x * V_DIM);
  float4* p4 = (float4*)(out + (size_t)blockIdx.x * V_DIM);
  const int t = threadIdx.x;
  __shared__ float sred[16];

  float4 v[8];
  float m = -1e30f;
#pragma unroll
  for (int j = 0; j < 4; ++j) {
    const int i = j * 1024 + t;        // f16x8 index, < 4000
    if (i < 4000) {
      const f16x8 h = L[i];
      v[2 * j].x     = (float)h[0]; v[2 * j].y     = (float)h[1];
      v[2 * j].z     = (float)h[2]; v[2 * j].w     = (float)h[3];
      v[2 * j + 1].x = (float)h[4]; v[2 * j + 1].y = (float)h[5];
      v[2 * j + 1].z = (float)h[6]; v[2 * j + 1].w = (float)h[7];
      m = fmaxf(m, fmaxf(fmaxf(v[2 * j].x, v[2 * j].y),
                         fmaxf(v[2 * j].z, v[2 * j].w)));
      m = fmaxf(m, fmaxf(fmaxf(v[2 * j + 1].x, v[2 * j + 1].y),
                         fmaxf(v[2 * j + 1].z, v[2 * j + 1].w)));
    }
  }
  m = waveMax(m);
  if ((t & 63) == 0) sred[t >> 6] = m;
  __syncthreads();
  float mb = sred[0];
#pragma unroll
  for (int k = 1; k < 16; ++k) mb = fmaxf(mb, sred[k]);
  __syncthreads();

  float s = 0.f;
#pragma unroll
  for (int j = 0; j < 8; ++j) {
    const int i = (j >> 1) * 1024 + t;
    if (i < 4000) {
      v[j].x = expf(v[j].x - mb);
      v[j].y = expf(v[j].y - mb);
      v[j].z = expf(v[j].z - mb);
      v[j].w = expf(v[j].w - mb);
      s += v[j].x + v[j].y + v[j].z + v[j].w;
    }
  }
  s = waveSum(s);
  if ((t & 63) == 0) sred[t >> 6] = s;
  __syncthreads();
  float sb = sred[0];
#pragma unroll
  for (int k = 1; k < 16; ++k) sb += sred[k];
  const float inv = 1.0f / sb;

#pragma unroll
  for (int j = 0; j < 4; ++j) {
    const int i = j * 1024 + t;
    if (i < 4000) {
      float4 a = v[2 * j], b = v[2 * j + 1];
      a.x *= inv; a.y *= inv; a.z *= inv; a.w *= inv;
      b.x *= inv; b.y *= inv; b.z *= inv; b.w *= inv;
      p4[2 * i] = a;
      p4[2 * i + 1] = b;
    }
  }
}

__global__ __launch_bounds__(1024) void softmax_reg_kernel(
    float* __restrict__ out) {
  float4* p4 = (float4*)(out + (size_t)blockIdx.x * V_DIM);
  const int t = threadIdx.x;
  __shared__ float sred[16];
  float4 v[8];
  float m = -1e30f;
#pragma unroll
  for (int j = 0; j < 8; ++j) {
    const int i = j * 1024 + t;
    if (i < 8000) {
      v[j] = p4[i];
      m = fmaxf(m, fmaxf(fmaxf(v[j].x, v[j].y), fmaxf(v[j].z, v[j].w)));
    }
  }
  m = waveMax(m);
  if ((t & 63) == 0) sred[t >> 6] = m;
  __syncthreads();
  float mb = sred[0];
#pragma unroll
  for (int k = 1; k < 16; ++k) mb = fmaxf(mb, sred[k]);
  __syncthreads();
  float s = 0.f;
#pragma unroll
  for (int j = 0; j < 8; ++j) {
    const int i = j * 1024 + t;
    if (i < 8000) {
      v[j].x = expf(v[j].x - mb);
      v[j].y = expf(v[j].y - mb);
      v[j].z = expf(v[j].z - mb);
      v[j].w = expf(v[j].w - mb);
      s += v[j].x + v[j].y + v[j].z + v[j].w;
    }
  }
  s = waveSum(s);
  if ((t & 63) == 0) sred[t >> 6] = s;
  __syncthreads();
  float sb = sred[0];
#pragma unroll
  for (int k = 1; k < 16; ++k) sb += sred[k];
  const float inv = 1.0f / sb;
#pragma unroll
  for (int j = 0; j < 8; ++j) {
    const int i = j * 1024 + t;
    if (i < 8000) {
      float4 o;
      o.x = v[j].x * inv; o.y = v[j].y * inv;
      o.z = v[j].z * inv; o.w = v[j].w * inv;
      p4[i] = o;
    }
  }
}

// ---------------------------------------------------------------------------
extern "C" void kernel_launch(void* const* d_in, const int* in_sizes, int n_in,
                              void* d_out, int out_size, void* d_ws, size_t ws_size,
                              hipStream_t stream) {
  const float* features = (const float*)d_in[0];
  const int*   captions = (const int*)d_in[1];
  const float* emb      = (const float*)d_in[3];
  const float* w_ih     = (const float*)d_in[4];
  const float* w_hh     = (const float*)d_in[5];
  const float* b_ih     = (const float*)d_in[6];
  const float* b_hh     = (const float*)d_in[7];
  const float* fc_w     = (const float*)d_in[8];
  const float* fc_b     = (const float*)d_in[9];
  float* out = (float*)d_out;

  // ---- d_ws layout ----
  char* ws = (char*)d_ws;
  unsigned* flags = (unsigned*)ws; ws += 512;                     // 128 flags
  f16* hsT = (f16*)ws;  ws += (size_t)21 * B_DIM * H_DIM * 2;     // 1.38 MB
  f16* w16 = (f16*)ws;  ws += (size_t)V_DIM * H_DIM * 2;          // 32.77 MB
  f16* logits16 = (f16*)ws;  // 81.92 MB if available
  const size_t ws_need_f16logits =
      ((char*)logits16 - (char*)d_ws) + (size_t)1280 * V_DIM * 2;  // ~116 MB
  const bool use_f16_logits = ws_size >= ws_need_f16logits;

  // ---- transient scratch in d_out (dead before final output writes) ----
  float* P     = out;                          // [1408][2048] f32, 11.5 MB
  f16*   x16   = (f16*)(out + 3000000);        // [1408][512] f16
  f16*   wih16 = (f16*)(out + 3400000);        // [2048][512] f16
  f16*   whh16 = (f16*)(out + 4000000);        // [2048][512] f16
  float* bsum  = out + 4600000;                // [2048] f32

  hipMemsetAsync(flags, 0, 512, stream);

  gather_x16_kernel<<<1408, 128, 0, stream>>>(features, captions, emb, x16);
  convert_w_kernel<<<1024, 256, 0, stream>>>(w_ih, wih16);
  convert_w_kernel<<<1024, 256, 0, stream>>>(w_hh, whh16);
  convert_w_kernel<<<16000, 256, 0, stream>>>(fc_w, w16);
  bias_sum_kernel<<<8, 256, 0, stream>>>(b_ih, b_hh, bsum);

  // proj: P[1408][2048] = x16 @ wih16^T + bsum   (rows t-major: m' = t*64+b)
  gemm16_kernel<<<dim3(16, 11), 256, 0, stream>>>(x16, wih16, bsum, P, 2048, 0);

  // all 21 LSTM steps, one kernel, flag-array barrier, h lives in hsT slabs
  lstm_persistent3<<<NBLK_LSTM, 256, 0, stream>>>(P, whh16, hsT, flags);

  // FC A = hsT slabs 1..20 (rows t-major), C rows remapped to b-major
  const f16* Afc = hsT + (size_t)B_DIM * H_DIM;
  if (use_f16_logits) {
    gemm16_f16out_kernel<<<dim3(250, 10), 256, 0, stream>>>(Afc, w16, fc_b,
                                                            logits16);
    softmax_f16_kernel<<<1280, 1024, 0, stream>>>(logits16, out);
  } else {
    gemm16_kernel<<<dim3(250, 10), 256, 0, stream>>>(Afc, w16, fc_b, out,
                                                     32000, 1);
    softmax_reg_kernel<<<1280, 1024, 0, stream>>>(out);
  }
}

// Round 11
// 408.348 us; speedup vs baseline: 1.0444x; 1.0263x over previous
//
#include <hip/hip_runtime.h>
#include <cstdint>
#include <cstddef>

#define E_DIM 512
#define H_DIM 512
#define V_DIM 32000
#define B_DIM 64
#define T_DIM 20
#define NBLK_LSTM 128
#define PT_STRIDE 68   // LDS pad: [21][16][68] f32

typedef _Float16 f16;
typedef _Float16 f16x8 __attribute__((ext_vector_type(8)));
typedef _Float16 f16x4 __attribute__((ext_vector_type(4)));
typedef float    f32x4 __attribute__((ext_vector_type(4)));

__device__ __forceinline__ void async_lds16(void* lds, const void* g) {
  __builtin_amdgcn_global_load_lds(
      (const __attribute__((address_space(1))) uint32_t*)g,
      (__attribute__((address_space(3))) uint32_t*)lds, 16, 0, 0);
}

__device__ __forceinline__ float sigmoidf_(float x) {
  return 1.0f / (1.0f + expf(-x));
}

// Agent-coherent (cross-XCD) accesses: relaxed atomics bypass the
// non-coherent per-XCD L2s and hit the coherence point (LLC).
__device__ __forceinline__ f16x8 load_h8_coh(const f16* p) {
  union { unsigned long long u[2]; f16x8 v; } r;
  r.u[0] = __hip_atomic_load((const unsigned long long*)p,
                             __ATOMIC_RELAXED, __HIP_MEMORY_SCOPE_AGENT);
  r.u[1] = __hip_atomic_load((const unsigned long long*)(p + 4),
                             __ATOMIC_RELAXED, __HIP_MEMORY_SCOPE_AGENT);
  return r.v;
}
__device__ __forceinline__ void store_h_coh(f16* p, float v) {
  union { f16 h; unsigned short s; } cvt;
  cvt.h = (f16)v;
  __hip_atomic_store((unsigned short*)p, cvt.s,
                     __ATOMIC_RELAXED, __HIP_MEMORY_SCOPE_AGENT);
}

// ---------------------------------------------------------------------------
// Gather x rows to fp16, T-MAJOR: x16[m'][512], m' = t*64 + b; rows
// 1344..1407 zero pad.
// ---------------------------------------------------------------------------
__global__ __launch_bounds__(128) void gather_x16_kernel(
    const float* __restrict__ features, const int* __restrict__ captions,
    const float* __restrict__ emb, f16* __restrict__ x16) {
  const int m = blockIdx.x;
  const int j = threadIdx.x;
  f16x4 r4 = {(f16)0.f, (f16)0.f, (f16)0.f, (f16)0.f};
  if (m < 1344) {
    const int b = m & 63;
    const int t = m >> 6;
    const float* src = (t == 0)
        ? features + (size_t)b * E_DIM
        : emb + (size_t)captions[b * T_DIM + (t - 1)] * E_DIM;
    const float4 v = ((const float4*)src)[j];
    r4.x = (f16)v.x; r4.y = (f16)v.y; r4.z = (f16)v.z; r4.w = (f16)v.w;
  }
  ((f16x4*)(x16 + (size_t)m * 512))[j] = r4;
}

__global__ __launch_bounds__(256) void convert_w_kernel(
    const float* __restrict__ w, f16* __restrict__ w16) {
  const int i = blockIdx.x * 256 + threadIdx.x;
  const float4 v = ((const float4*)w)[i];
  f16x4 r;
  r.x = (f16)v.x; r.y = (f16)v.y; r.z = (f16)v.z; r.w = (f16)v.w;
  ((f16x4*)w16)[i] = r;
}

__global__ __launch_bounds__(256) void bias_sum_kernel(
    const float* __restrict__ a, const float* __restrict__ b,
    float* __restrict__ o) {
  const int i = blockIdx.x * 256 + threadIdx.x;
  if (i < 2048) o[i] = a[i] + b[i];
}

// ---------------------------------------------------------------------------
// K=512 fp16 GEMM (B^T form): C = A.Bw^T + bias. 128x128 tile, BK=64,
// 4 waves (2x2), 16x16x32 f16 MFMA, global_load_lds.
// mode 0: C[m][n] (ldc)      mode 1: FC fallback, C row = (m&63)*20+(m>>6)
// mode 2: proj P_T write: off = (m>>6)*131072 + n*64 + (m&63)   [t][gr][b]
// ---------------------------------------------------------------------------
__global__ __launch_bounds__(256) void gemm16_kernel(
    const f16* __restrict__ A, const f16* __restrict__ Bw,
    const float* __restrict__ bias, float* __restrict__ C, int ldc,
    int mode) {
  __shared__ f16 As[128 * 64];
  __shared__ f16 Bs[128 * 64];
  const int tid = threadIdx.x;
  const int lane = tid & 63;
  const int wid = tid >> 6;
  const int m0 = blockIdx.y * 128;
  const int n0 = blockIdx.x * 128;
  const int wm = (wid >> 1) * 64;
  const int wn = (wid & 1) * 64;

  f32x4 acc[4][4];
#pragma unroll
  for (int i = 0; i < 4; ++i)
#pragma unroll
    for (int j = 0; j < 4; ++j) {
      f32x4 z = {0.f, 0.f, 0.f, 0.f};
      acc[i][j] = z;
    }
  const int lr = lane & 15;
  const int lkb = (lane >> 4) * 8;

  for (int kt = 0; kt < 512; kt += 64) {
#pragma unroll
    for (int i = 0; i < 4; ++i) {
      const int off = i * 4096 + wid * 1024 + lane * 16;
      const int row = off >> 7;
      const int colh = (off & 127) >> 1;
      async_lds16((char*)As + i * 4096 + wid * 1024,
                  A + (size_t)(m0 + row) * 512 + kt + colh);
      async_lds16((char*)Bs + i * 4096 + wid * 1024,
                  Bw + (size_t)(n0 + row) * 512 + kt + colh);
    }
    __syncthreads();
#pragma unroll
    for (int ks = 0; ks < 2; ++ks) {
      f16x8 af[4], bf[4];
#pragma unroll
      for (int mi = 0; mi < 4; ++mi)
        af[mi] = *(const f16x8*)&As[(wm + mi * 16 + lr) * 64 + ks * 32 + lkb];
#pragma unroll
      for (int ni = 0; ni < 4; ++ni)
        bf[ni] = *(const f16x8*)&Bs[(wn + ni * 16 + lr) * 64 + ks * 32 + lkb];
#pragma unroll
      for (int mi = 0; mi < 4; ++mi)
#pragma unroll
        for (int ni = 0; ni < 4; ++ni)
          acc[mi][ni] = __builtin_amdgcn_mfma_f32_16x16x32_f16(
              af[mi], bf[ni], acc[mi][ni], 0, 0, 0);
    }
    __syncthreads();
  }

#pragma unroll
  for (int mi = 0; mi < 4; ++mi) {
    const int mbase = m0 + wm + mi * 16 + (lane >> 4) * 4;
#pragma unroll
    for (int ni = 0; ni < 4; ++ni) {
      const int n = n0 + wn + ni * 16 + lr;
      const float bv = bias[n];
#pragma unroll
      for (int r = 0; r < 4; ++r) {
        const int mr = mbase + r;
        size_t off;
        if (mode == 2)
          off = (size_t)(mr >> 6) * (2048 * 64) + (size_t)n * 64 + (mr & 63);
        else if (mode == 1)
          off = (size_t)((mr & 63) * 20 + (mr >> 6)) * ldc + n;
        else
          off = (size_t)mr * ldc + n;
        C[off] = acc[mi][ni][r] + bv;
      }
    }
  }
}

// Same GEMM, f16 C output, FC-only (ldc=32000, rows remapped to b-major).
__global__ __launch_bounds__(256) void gemm16_f16out_kernel(
    const f16* __restrict__ A, const f16* __restrict__ Bw,
    const float* __restrict__ bias, f16* __restrict__ C16) {
  __shared__ f16 As[128 * 64];
  __shared__ f16 Bs[128 * 64];
  const int tid = threadIdx.x;
  const int lane = tid & 63;
  const int wid = tid >> 6;
  const int m0 = blockIdx.y * 128;
  const int n0 = blockIdx.x * 128;
  const int wm = (wid >> 1) * 64;
  const int wn = (wid & 1) * 64;

  f32x4 acc[4][4];
#pragma unroll
  for (int i = 0; i < 4; ++i)
#pragma unroll
    for (int j = 0; j < 4; ++j) {
      f32x4 z = {0.f, 0.f, 0.f, 0.f};
      acc[i][j] = z;
    }
  const int lr = lane & 15;
  const int lkb = (lane >> 4) * 8;

  for (int kt = 0; kt < 512; kt += 64) {
#pragma unroll
    for (int i = 0; i < 4; ++i) {
      const int off = i * 4096 + wid * 1024 + lane * 16;
      const int row = off >> 7;
      const int colh = (off & 127) >> 1;
      async_lds16((char*)As + i * 4096 + wid * 1024,
                  A + (size_t)(m0 + row) * 512 + kt + colh);
      async_lds16((char*)Bs + i * 4096 + wid * 1024,
                  Bw + (size_t)(n0 + row) * 512 + kt + colh);
    }
    __syncthreads();
#pragma unroll
    for (int ks = 0; ks < 2; ++ks) {
      f16x8 af[4], bf[4];
#pragma unroll
      for (int mi = 0; mi < 4; ++mi)
        af[mi] = *(const f16x8*)&As[(wm + mi * 16 + lr) * 64 + ks * 32 + lkb];
#pragma unroll
      for (int ni = 0; ni < 4; ++ni)
        bf[ni] = *(const f16x8*)&Bs[(wn + ni * 16 + lr) * 64 + ks * 32 + lkb];
#pragma unroll
      for (int mi = 0; mi < 4; ++mi)
#pragma unroll
        for (int ni = 0; ni < 4; ++ni)
          acc[mi][ni] = __builtin_amdgcn_mfma_f32_16x16x32_f16(
              af[mi], bf[ni], acc[mi][ni], 0, 0, 0);
    }
    __syncthreads();
  }

#pragma unroll
  for (int mi = 0; mi < 4; ++mi) {
    const int mbase = m0 + wm + mi * 16 + (lane >> 4) * 4;
#pragma unroll
    for (int ni = 0; ni < 4; ++ni) {
      const int n = n0 + wn + ni * 16 + lr;
      const float bv = bias[n];
#pragma unroll
      for (int r = 0; r < 4; ++r) {
        const int mr = mbase + r;
        const int orow = (mr & 63) * 20 + (mr >> 6);
        C16[(size_t)orow * 32000 + n] = (f16)(acc[mi][ni][r] + bv);
      }
    }
  }
}

// ---------------------------------------------------------------------------
// Persistent LSTM v4: 21 steps, ONE kernel. Block's P slice ([21][16 gate-
// rows][64 b] = 89KB) staged ONCE from P_T into LDS with fully-coalesced
// 256B-row reads; per-step P access is LDS-only (this removes the 49MB
// scattered HBM fetch that bound v3 at 238 GB/s). Flag-array barrier;
// h via agent-coherent atomics in t-major hsT slabs; c in registers.
// ---------------------------------------------------------------------------
__global__ __launch_bounds__(256) void lstm_persistent4(
    const float* __restrict__ PT, const f16* __restrict__ Whh,
    f16* __restrict__ hsT, unsigned* __restrict__ flags) {
  __shared__ float pS[21 * 16 * PT_STRIDE];   // 89.25 KB
  const int tid = threadIdx.x;
  const int lane = tid & 63;
  const int w = tid >> 6;
  const int u0 = blockIdx.x * 4;
  const int fr = lane & 15;
  const int fq = lane >> 4;
  const int grow = (fr >> 2) * 512 + u0 + (fr & 3);
  const f16* brow = Whh + (size_t)grow * 512;  // L2-hot across all steps

  // stage P slice: for t<21, rr<16 (g=rr>>2, j=rr&3), 64 b-floats per row.
  // i -> (t, rr, q4); 16 consecutive tids read one 256B row coalesced.
  for (int i = tid; i < 21 * 16 * 16; i += 256) {
    const int t = i >> 8;
    const int rr = (i & 255) >> 4;
    const int q4 = i & 15;
    const int gr = (rr >> 2) * 512 + u0 + (rr & 3);
    const float4 v = *(const float4*)&PT[((size_t)t * 2048 + gr) * 64 + q4 * 4];
    *(float4*)&pS[(t * 16 + rr) * PT_STRIDE + q4 * 4] = v;
  }
  __syncthreads();

  float cr[4] = {0.f, 0.f, 0.f, 0.f};  // c for (b = w*16+fq*4+r, u = u0+fr)

  for (int t = 0; t <= T_DIM; ++t) {
    f32x4 acc = {0.f, 0.f, 0.f, 0.f};
    if (t > 0) {
      const f16* arow = hsT + (size_t)(t - 1) * (64 * 512)
                            + (size_t)(w * 16 + fr) * 512;
      f16x8 a[16], b[16];
#pragma unroll
      for (int kk = 0; kk < 16; ++kk) {
        const int kc = kk * 32 + fq * 8;
        a[kk] = load_h8_coh(&arow[kc]);
        b[kk] = *(const f16x8*)&brow[kc];
      }
#pragma unroll
      for (int kk = 0; kk < 16; ++kk)
        acc = __builtin_amdgcn_mfma_f32_16x16x32_f16(a[kk], b[kk], acc,
                                                     0, 0, 0);
    }
    // add input projection + biases from LDS: pS[t][fr][b]
#pragma unroll
    for (int r = 0; r < 4; ++r) {
      const int b = w * 16 + fq * 4 + r;
      acc[r] += pS[(t * 16 + fr) * PT_STRIDE + b];
    }

    f16* hout = hsT + (size_t)t * (64 * 512);
#pragma unroll
    for (int r = 0; r < 4; ++r) {
      const float x  = acc[r];
      const float xf = __shfl_xor(x, 4);
      const float xg = __shfl_xor(x, 8);
      const float xo = __shfl_xor(x, 12);
      if (fr < 4) {
        const int b = w * 16 + fq * 4 + r;
        const int u = u0 + fr;
        const float si = sigmoidf_(x);
        const float sf = sigmoidf_(xf);
        const float tg = tanhf(xg);
        const float so = sigmoidf_(xo);
        const float cn = sf * cr[r] + si * tg;
        cr[r] = cn;
        const float hn = so * tanhf(cn);
        store_h_coh(&hout[(size_t)b * 512 + u], hn);
      }
    }

    if (t < T_DIM) {
      // drain own coherent stores, then contention-free flag barrier.
      asm volatile("s_waitcnt vmcnt(0)" ::: "memory");
      __syncthreads();
      if (tid == 0)
        __hip_atomic_store(&flags[blockIdx.x], (unsigned)(t + 1),
                           __ATOMIC_RELAXED, __HIP_MEMORY_SCOPE_AGENT);
      if (tid < NBLK_LSTM) {
        while (__hip_atomic_load(&flags[tid], __ATOMIC_RELAXED,
                                 __HIP_MEMORY_SCOPE_AGENT) < (unsigned)(t + 1))
          __builtin_amdgcn_s_sleep(2);
      }
      __syncthreads();
    }
  }
}

// ---------------------------------------------------------------------------
// Softmax over V=32000, row in registers (1024 thr). f16-logit input variant
// and f32 in-place fallback.
// ---------------------------------------------------------------------------
__device__ __forceinline__ float waveMax(float v) {
#pragma unroll
  for (int o = 32; o > 0; o >>= 1) v = fmaxf(v, __shfl_down(v, o));
  return v;
}
__device__ __forceinline__ float waveSum(float v) {
#pragma unroll
  for (int o = 32; o > 0; o >>= 1) v += __shfl_down(v, o);
  return v;
}

__global__ __launch_bounds__(1024) void softmax_f16_kernel(
    const f16* __restrict__ lg, float* __restrict__ out) {
  const f16x8* L = (const f16x8*)(lg + (size_t)blockIdx.x * V_DIM);
  float4* p4 = (float4*)(out + (size_t)blockIdx.x * V_DIM);
  const int t = threadIdx.x;
  __shared__ float sred[16];

  float4 v[8];
  float m = -1e30f;
#pragma unroll
  for (int j = 0; j < 4; ++j) {
    const int i = j * 1024 + t;        // f16x8 index, < 4000
    if (i < 4000) {
      const f16x8 h = L[i];
      v[2 * j].x     = (float)h[0]; v[2 * j].y     = (float)h[1];
      v[2 * j].z     = (float)h[2]; v[2 * j].w     = (float)h[3];
      v[2 * j + 1].x = (float)h[4]; v[2 * j + 1].y = (float)h[5];
      v[2 * j + 1].z = (float)h[6]; v[2 * j + 1].w = (float)h[7];
      m = fmaxf(m, fmaxf(fmaxf(v[2 * j].x, v[2 * j].y),
                         fmaxf(v[2 * j].z, v[2 * j].w)));
      m = fmaxf(m, fmaxf(fmaxf(v[2 * j + 1].x, v[2 * j + 1].y),
                         fmaxf(v[2 * j + 1].z, v[2 * j + 1].w)));
    }
  }
  m = waveMax(m);
  if ((t & 63) == 0) sred[t >> 6] = m;
  __syncthreads();
  float mb = sred[0];
#pragma unroll
  for (int k = 1; k < 16; ++k) mb = fmaxf(mb, sred[k]);
  __syncthreads();

  float s = 0.f;
#pragma unroll
  for (int j = 0; j < 8; ++j) {
    const int i = (j >> 1) * 1024 + t;
    if (i < 4000) {
      v[j].x = expf(v[j].x - mb);
      v[j].y = expf(v[j].y - mb);
      v[j].z = expf(v[j].z - mb);
      v[j].w = expf(v[j].w - mb);
      s += v[j].x + v[j].y + v[j].z + v[j].w;
    }
  }
  s = waveSum(s);
  if ((t & 63) == 0) sred[t >> 6] = s;
  __syncthreads();
  float sb = sred[0];
#pragma unroll
  for (int k = 1; k < 16; ++k) sb += sred[k];
  const float inv = 1.0f / sb;

#pragma unroll
  for (int j = 0; j < 4; ++j) {
    const int i = j * 1024 + t;
    if (i < 4000) {
      float4 a = v[2 * j], b = v[2 * j + 1];
      a.x *= inv; a.y *= inv; a.z *= inv; a.w *= inv;
      b.x *= inv; b.y *= inv; b.z *= inv; b.w *= inv;
      p4[2 * i] = a;
      p4[2 * i + 1] = b;
    }
  }
}

__global__ __launch_bounds__(1024) void softmax_reg_kernel(
    float* __restrict__ out) {
  float4* p4 = (float4*)(out + (size_t)blockIdx.x * V_DIM);
  const int t = threadIdx.x;
  __shared__ float sred[16];
  float4 v[8];
  float m = -1e30f;
#pragma unroll
  for (int j = 0; j < 8; ++j) {
    const int i = j * 1024 + t;
    if (i < 8000) {
      v[j] = p4[i];
      m = fmaxf(m, fmaxf(fmaxf(v[j].x, v[j].y), fmaxf(v[j].z, v[j].w)));
    }
  }
  m = waveMax(m);
  if ((t & 63) == 0) sred[t >> 6] = m;
  __syncthreads();
  float mb = sred[0];
#pragma unroll
  for (int k = 1; k < 16; ++k) mb = fmaxf(mb, sred[k]);
  __syncthreads();
  float s = 0.f;
#pragma unroll
  for (int j = 0; j < 8; ++j) {
    const int i = j * 1024 + t;
    if (i < 8000) {
      v[j].x = expf(v[j].x - mb);
      v[j].y = expf(v[j].y - mb);
      v[j].z = expf(v[j].z - mb);
      v[j].w = expf(v[j].w - mb);
      s += v[j].x + v[j].y + v[j].z + v[j].w;
    }
  }
  s = waveSum(s);
  if ((t & 63) == 0) sred[t >> 6] = s;
  __syncthreads();
  float sb = sred[0];
#pragma unroll
  for (int k = 1; k < 16; ++k) sb += sred[k];
  const float inv = 1.0f / sb;
#pragma unroll
  for (int j = 0; j < 8; ++j) {
    const int i = j * 1024 + t;
    if (i < 8000) {
      float4 o;
      o.x = v[j].x * inv; o.y = v[j].y * inv;
      o.z = v[j].z * inv; o.w = v[j].w * inv;
      p4[i] = o;
    }
  }
}

// ---------------------------------------------------------------------------
extern "C" void kernel_launch(void* const* d_in, const int* in_sizes, int n_in,
                              void* d_out, int out_size, void* d_ws, size_t ws_size,
                              hipStream_t stream) {
  const float* features = (const float*)d_in[0];
  const int*   captions = (const int*)d_in[1];
  const float* emb      = (const float*)d_in[3];
  const float* w_ih     = (const float*)d_in[4];
  const float* w_hh     = (const float*)d_in[5];
  const float* b_ih     = (const float*)d_in[6];
  const float* b_hh     = (const float*)d_in[7];
  const float* fc_w     = (const float*)d_in[8];
  const float* fc_b     = (const float*)d_in[9];
  float* out = (float*)d_out;

  // ---- d_ws layout ----
  char* ws = (char*)d_ws;
  unsigned* flags = (unsigned*)ws; ws += 512;                     // 128 flags
  f16* hsT = (f16*)ws;  ws += (size_t)21 * B_DIM * H_DIM * 2;     // 1.38 MB
  f16* w16 = (f16*)ws;  ws += (size_t)V_DIM * H_DIM * 2;          // 32.77 MB
  f16* logits16 = (f16*)ws;  // 81.92 MB if available
  const size_t ws_need_f16logits =
      ((char*)logits16 - (char*)d_ws) + (size_t)1280 * V_DIM * 2;  // ~116 MB
  const bool use_f16_logits = ws_size >= ws_need_f16logits;

  // ---- transient scratch in d_out (dead before final output writes) ----
  // P_T [22 slabs max][2048][64] f32 = 11.5 MB (slab 21 = pad rows, unused)
  float* PT    = out;
  f16*   x16   = (f16*)(out + 3000000);        // [1408][512] f16
  f16*   wih16 = (f16*)(out + 3400000);        // [2048][512] f16
  f16*   whh16 = (f16*)(out + 4000000);        // [2048][512] f16
  float* bsum  = out + 4600000;                // [2048] f32

  hipMemsetAsync(flags, 0, 512, stream);

  gather_x16_kernel<<<1408, 128, 0, stream>>>(features, captions, emb, x16);
  convert_w_kernel<<<1024, 256, 0, stream>>>(w_ih, wih16);
  convert_w_kernel<<<1024, 256, 0, stream>>>(w_hh, whh16);
  convert_w_kernel<<<16000, 256, 0, stream>>>(fc_w, w16);
  bias_sum_kernel<<<8, 256, 0, stream>>>(b_ih, b_hh, bsum);

  // proj -> P_T[t][gate-row][b]  (mode 2 epilogue)
  gemm16_kernel<<<dim3(16, 11), 256, 0, stream>>>(x16, wih16, bsum, PT, 0, 2);

  // all 21 LSTM steps, one kernel; per-step P reads are LDS-only
  lstm_persistent4<<<NBLK_LSTM, 256, 0, stream>>>(PT, whh16, hsT, flags);

  // FC A = hsT slabs 1..20 (rows t-major), C rows remapped to b-major
  const f16* Afc = hsT + (size_t)B_DIM * H_DIM;
  if (use_f16_logits) {
    gemm16_f16out_kernel<<<dim3(250, 10), 256, 0, stream>>>(Afc, w16, fc_b,
                                                            logits16);
    softmax_f16_kernel<<<1280, 1024, 0, stream>>>(logits16, out);
  } else {
    gemm16_kernel<<<dim3(250, 10), 256, 0, stream>>>(Afc, w16, fc_b, out,
                                                     32000, 1);
    softmax_reg_kernel<<<1280, 1024, 0, stream>>>(out);
  }
}

// Round 12
// 334.768 us; speedup vs baseline: 1.2740x; 1.2198x over previous
//
#include <hip/hip_runtime.h>
#include <cstdint>
#include <cstddef>

#define E_DIM 512
#define H_DIM 512
#define V_DIM 32000
#define B_DIM 64
#define T_DIM 20
#define NBLK_LSTM 128
#define PT_STRIDE 68   // LDS pad: [21][16][68] f32

typedef _Float16 f16;
typedef _Float16 f16x8 __attribute__((ext_vector_type(8)));
typedef _Float16 f16x4 __attribute__((ext_vector_type(4)));
typedef float    f32x4 __attribute__((ext_vector_type(4)));

__device__ __forceinline__ void async_lds16(void* lds, const void* g) {
  __builtin_amdgcn_global_load_lds(
      (const __attribute__((address_space(1))) uint32_t*)g,
      (__attribute__((address_space(3))) uint32_t*)lds, 16, 0, 0);
}

__device__ __forceinline__ float sigmoidf_(float x) {
  return 1.0f / (1.0f + expf(-x));
}

// Agent-coherent (cross-XCD) accesses: relaxed atomics bypass the
// non-coherent per-XCD L2s and hit the coherence point (LLC).
__device__ __forceinline__ f16x8 load_h8_coh(const f16* p) {
  union { unsigned long long u[2]; f16x8 v; } r;
  r.u[0] = __hip_atomic_load((const unsigned long long*)p,
                             __ATOMIC_RELAXED, __HIP_MEMORY_SCOPE_AGENT);
  r.u[1] = __hip_atomic_load((const unsigned long long*)(p + 4),
                             __ATOMIC_RELAXED, __HIP_MEMORY_SCOPE_AGENT);
  return r.v;
}
__device__ __forceinline__ void store_h_coh(f16* p, float v) {
  union { f16 h; unsigned short s; } cvt;
  cvt.h = (f16)v;
  __hip_atomic_store((unsigned short*)p, cvt.s,
                     __ATOMIC_RELAXED, __HIP_MEMORY_SCOPE_AGENT);
}

// ---------------------------------------------------------------------------
// Gather x rows to fp16, T-MAJOR: x16[m'][512], m' = t*64 + b; rows
// 1344..1407 zero pad.
// ---------------------------------------------------------------------------
__global__ __launch_bounds__(128) void gather_x16_kernel(
    const float* __restrict__ features, const int* __restrict__ captions,
    const float* __restrict__ emb, f16* __restrict__ x16) {
  const int m = blockIdx.x;
  const int j = threadIdx.x;
  f16x4 r4 = {(f16)0.f, (f16)0.f, (f16)0.f, (f16)0.f};
  if (m < 1344) {
    const int b = m & 63;
    const int t = m >> 6;
    const float* src = (t == 0)
        ? features + (size_t)b * E_DIM
        : emb + (size_t)captions[b * T_DIM + (t - 1)] * E_DIM;
    const float4 v = ((const float4*)src)[j];
    r4.x = (f16)v.x; r4.y = (f16)v.y; r4.z = (f16)v.z; r4.w = (f16)v.w;
  }
  ((f16x4*)(x16 + (size_t)m * 512))[j] = r4;
}

__global__ __launch_bounds__(256) void convert_w_kernel(
    const float* __restrict__ w, f16* __restrict__ w16) {
  const int i = blockIdx.x * 256 + threadIdx.x;
  const float4 v = ((const float4*)w)[i];
  f16x4 r;
  r.x = (f16)v.x; r.y = (f16)v.y; r.z = (f16)v.z; r.w = (f16)v.w;
  ((f16x4*)w16)[i] = r;
}

__global__ __launch_bounds__(256) void bias_sum_kernel(
    const float* __restrict__ a, const float* __restrict__ b,
    float* __restrict__ o) {
  const int i = blockIdx.x * 256 + threadIdx.x;
  if (i < 2048) o[i] = a[i] + b[i];
}

// ---------------------------------------------------------------------------
// K=512 fp16 GEMM (B^T form): C = A.Bw^T + bias. 128x128 tile, BK=64,
// 4 waves (2x2), 16x16x32 f16 MFMA, global_load_lds.
// mode 0: C[m][n] (ldc)      mode 1: FC fallback, C row = (m&63)*20+(m>>6)
// mode 2: proj P_T write: off = (m>>6)*131072 + n*64 + (m&63)   [t][gr][b]
// ---------------------------------------------------------------------------
__global__ __launch_bounds__(256) void gemm16_kernel(
    const f16* __restrict__ A, const f16* __restrict__ Bw,
    const float* __restrict__ bias, float* __restrict__ C, int ldc,
    int mode) {
  __shared__ f16 As[128 * 64];
  __shared__ f16 Bs[128 * 64];
  const int tid = threadIdx.x;
  const int lane = tid & 63;
  const int wid = tid >> 6;
  const int m0 = blockIdx.y * 128;
  const int n0 = blockIdx.x * 128;
  const int wm = (wid >> 1) * 64;
  const int wn = (wid & 1) * 64;

  f32x4 acc[4][4];
#pragma unroll
  for (int i = 0; i < 4; ++i)
#pragma unroll
    for (int j = 0; j < 4; ++j) {
      f32x4 z = {0.f, 0.f, 0.f, 0.f};
      acc[i][j] = z;
    }
  const int lr = lane & 15;
  const int lkb = (lane >> 4) * 8;

  for (int kt = 0; kt < 512; kt += 64) {
#pragma unroll
    for (int i = 0; i < 4; ++i) {
      const int off = i * 4096 + wid * 1024 + lane * 16;
      const int row = off >> 7;
      const int colh = (off & 127) >> 1;
      async_lds16((char*)As + i * 4096 + wid * 1024,
                  A + (size_t)(m0 + row) * 512 + kt + colh);
      async_lds16((char*)Bs + i * 4096 + wid * 1024,
                  Bw + (size_t)(n0 + row) * 512 + kt + colh);
    }
    __syncthreads();
#pragma unroll
    for (int ks = 0; ks < 2; ++ks) {
      f16x8 af[4], bf[4];
#pragma unroll
      for (int mi = 0; mi < 4; ++mi)
        af[mi] = *(const f16x8*)&As[(wm + mi * 16 + lr) * 64 + ks * 32 + lkb];
#pragma unroll
      for (int ni = 0; ni < 4; ++ni)
        bf[ni] = *(const f16x8*)&Bs[(wn + ni * 16 + lr) * 64 + ks * 32 + lkb];
#pragma unroll
      for (int mi = 0; mi < 4; ++mi)
#pragma unroll
        for (int ni = 0; ni < 4; ++ni)
          acc[mi][ni] = __builtin_amdgcn_mfma_f32_16x16x32_f16(
              af[mi], bf[ni], acc[mi][ni], 0, 0, 0);
    }
    __syncthreads();
  }

#pragma unroll
  for (int mi = 0; mi < 4; ++mi) {
    const int mbase = m0 + wm + mi * 16 + (lane >> 4) * 4;
#pragma unroll
    for (int ni = 0; ni < 4; ++ni) {
      const int n = n0 + wn + ni * 16 + lr;
      const float bv = bias[n];
#pragma unroll
      for (int r = 0; r < 4; ++r) {
        const int mr = mbase + r;
        size_t off;
        if (mode == 2)
          off = (size_t)(mr >> 6) * (2048 * 64) + (size_t)n * 64 + (mr & 63);
        else if (mode == 1)
          off = (size_t)((mr & 63) * 20 + (mr >> 6)) * ldc + n;
        else
          off = (size_t)mr * ldc + n;
        C[off] = acc[mi][ni][r] + bv;
      }
    }
  }
}

// Same GEMM, f16 C output, FC-only (ldc=32000, rows remapped to b-major).
__global__ __launch_bounds__(256) void gemm16_f16out_kernel(
    const f16* __restrict__ A, const f16* __restrict__ Bw,
    const float* __restrict__ bias, f16* __restrict__ C16) {
  __shared__ f16 As[128 * 64];
  __shared__ f16 Bs[128 * 64];
  const int tid = threadIdx.x;
  const int lane = tid & 63;
  const int wid = tid >> 6;
  const int m0 = blockIdx.y * 128;
  const int n0 = blockIdx.x * 128;
  const int wm = (wid >> 1) * 64;
  const int wn = (wid & 1) * 64;

  f32x4 acc[4][4];
#pragma unroll
  for (int i = 0; i < 4; ++i)
#pragma unroll
    for (int j = 0; j < 4; ++j) {
      f32x4 z = {0.f, 0.f, 0.f, 0.f};
      acc[i][j] = z;
    }
  const int lr = lane & 15;
  const int lkb = (lane >> 4) * 8;

  for (int kt = 0; kt < 512; kt += 64) {
#pragma unroll
    for (int i = 0; i < 4; ++i) {
      const int off = i * 4096 + wid * 1024 + lane * 16;
      const int row = off >> 7;
      const int colh = (off & 127) >> 1;
      async_lds16((char*)As + i * 4096 + wid * 1024,
                  A + (size_t)(m0 + row) * 512 + kt + colh);
      async_lds16((char*)Bs + i * 4096 + wid * 1024,
                  Bw + (size_t)(n0 + row) * 512 + kt + colh);
    }
    __syncthreads();
#pragma unroll
    for (int ks = 0; ks < 2; ++ks) {
      f16x8 af[4], bf[4];
#pragma unroll
      for (int mi = 0; mi < 4; ++mi)
        af[mi] = *(const f16x8*)&As[(wm + mi * 16 + lr) * 64 + ks * 32 + lkb];
#pragma unroll
      for (int ni = 0; ni < 4; ++ni)
        bf[ni] = *(const f16x8*)&Bs[(wn + ni * 16 + lr) * 64 + ks * 32 + lkb];
#pragma unroll
      for (int mi = 0; mi < 4; ++mi)
#pragma unroll
        for (int ni = 0; ni < 4; ++ni)
          acc[mi][ni] = __builtin_amdgcn_mfma_f32_16x16x32_f16(
              af[mi], bf[ni], acc[mi][ni], 0, 0, 0);
    }
    __syncthreads();
  }

#pragma unroll
  for (int mi = 0; mi < 4; ++mi) {
    const int mbase = m0 + wm + mi * 16 + (lane >> 4) * 4;
#pragma unroll
    for (int ni = 0; ni < 4; ++ni) {
      const int n = n0 + wn + ni * 16 + lr;
      const float bv = bias[n];
#pragma unroll
      for (int r = 0; r < 4; ++r) {
        const int mr = mbase + r;
        const int orow = (mr & 63) * 20 + (mr >> 6);
        C16[(size_t)orow * 32000 + n] = (f16)(acc[mi][ni][r] + bv);
      }
    }
  }
}

// ---------------------------------------------------------------------------
// Persistent LSTM v5. Fix vs v4: the per-step h fragment loads were 64-way
// per-lane scatters (16 rows x 1KB stride per instruction -> 524K 8B LLC
// requests/step). Now each wave stages its 16 h rows (contiguous 16KB)
// into LDS with LANE-CONTIGUOUS coherent loads (one row per instruction,
// fully coalesced), and MFMA A-fragments read from LDS. W fragments are
// hoisted into VGPRs once (reused across all 20 steps; scatter paid once).
// pS (P slice in LDS), flag-array barrier, coherent 2B h stores unchanged.
// LDS: pS 91.4KB + hS 66.6KB = 158KB -> 1 block/CU.
// ---------------------------------------------------------------------------
__global__ __launch_bounds__(256, 1) void lstm_persistent5(
    const float* __restrict__ PT, const f16* __restrict__ Whh,
    f16* __restrict__ hsT, unsigned* __restrict__ flags) {
  __shared__ float pS[21 * 16 * PT_STRIDE];   // 91.4 KB
  __shared__ f16 hS[64 * 520];                // 66.6 KB (wave-private 16-row bands)
  const int tid = threadIdx.x;
  const int lane = tid & 63;
  const int w = tid >> 6;
  const int u0 = blockIdx.x * 4;
  const int fr = lane & 15;
  const int fq = lane >> 4;
  const int grow = (fr >> 2) * 512 + u0 + (fr & 3);

  // W fragments -> VGPRs once (16 KB slice, reused all steps)
  f16x8 bW[16];
  {
    const f16* brow = Whh + (size_t)grow * 512;
#pragma unroll
    for (int kk = 0; kk < 16; ++kk)
      bW[kk] = *(const f16x8*)&brow[kk * 32 + fq * 8];
  }

  // stage P slice (one-time, coalesced 256B rows)
  for (int i = tid; i < 21 * 16 * 16; i += 256) {
    const int t = i >> 8;
    const int rr = (i & 255) >> 4;
    const int q4 = i & 15;
    const int gr = (rr >> 2) * 512 + u0 + (rr & 3);
    const float4 v = *(const float4*)&PT[((size_t)t * 2048 + gr) * 64 + q4 * 4];
    *(float4*)&pS[(t * 16 + rr) * PT_STRIDE + q4 * 4] = v;
  }
  __syncthreads();

  float cr[4] = {0.f, 0.f, 0.f, 0.f};  // c for (b = w*16+fq*4+r, u = u0+fr)

  for (int t = 0; t <= T_DIM; ++t) {
    f32x4 acc = {0.f, 0.f, 0.f, 0.f};
    if (t > 0) {
      // coalesced coherent stage: wave's 16 rows = contiguous 16KB of slab.
      // iteration j loads row j: 64 lanes x 16B (lane-contiguous).
      const f16* src = hsT + (size_t)(t - 1) * (64 * 512)
                           + (size_t)(w * 16) * 512;
      f16x8 hrow[16];
#pragma unroll
      for (int j = 0; j < 16; ++j)
        hrow[j] = load_h8_coh(src + (size_t)j * 512 + lane * 8);
#pragma unroll
      for (int j = 0; j < 16; ++j)
        *(f16x8*)&hS[(w * 16 + j) * 520 + lane * 8] = hrow[j];
      // hS band is wave-private: ds_write -> ds_read same wave, compiler
      // inserts the lgkmcnt; no __syncthreads needed.
      f16x8 a[16];
#pragma unroll
      for (int kk = 0; kk < 16; ++kk)
        a[kk] = *(const f16x8*)&hS[(w * 16 + fr) * 520 + kk * 32 + fq * 8];
#pragma unroll
      for (int kk = 0; kk < 16; ++kk)
        acc = __builtin_amdgcn_mfma_f32_16x16x32_f16(a[kk], bW[kk], acc,
                                                     0, 0, 0);
    }
    // add input projection + biases from LDS: pS[t][fr][b]
#pragma unroll
    for (int r = 0; r < 4; ++r) {
      const int b = w * 16 + fq * 4 + r;
      acc[r] += pS[(t * 16 + fr) * PT_STRIDE + b];
    }

    f16* hout = hsT + (size_t)t * (64 * 512);
#pragma unroll
    for (int r = 0; r < 4; ++r) {
      const float x  = acc[r];
      const float xf = __shfl_xor(x, 4);
      const float xg = __shfl_xor(x, 8);
      const float xo = __shfl_xor(x, 12);
      if (fr < 4) {
        const int b = w * 16 + fq * 4 + r;
        const int u = u0 + fr;
        const float si = sigmoidf_(x);
        const float sf = sigmoidf_(xf);
        const float tg = tanhf(xg);
        const float so = sigmoidf_(xo);
        const float cn = sf * cr[r] + si * tg;
        cr[r] = cn;
        const float hn = so * tanhf(cn);
        store_h_coh(&hout[(size_t)b * 512 + u], hn);
      }
    }

    if (t < T_DIM) {
      // drain own coherent stores, then contention-free flag barrier.
      asm volatile("s_waitcnt vmcnt(0)" ::: "memory");
      __syncthreads();
      if (tid == 0)
        __hip_atomic_store(&flags[blockIdx.x], (unsigned)(t + 1),
                           __ATOMIC_RELAXED, __HIP_MEMORY_SCOPE_AGENT);
      if (tid < NBLK_LSTM) {
        while (__hip_atomic_load(&flags[tid], __ATOMIC_RELAXED,
                                 __HIP_MEMORY_SCOPE_AGENT) < (unsigned)(t + 1))
          __builtin_amdgcn_s_sleep(2);
      }
      __syncthreads();
    }
  }
}

// ---------------------------------------------------------------------------
// Softmax over V=32000, row in registers (1024 thr). f16-logit input variant
// and f32 in-place fallback.
// ---------------------------------------------------------------------------
__device__ __forceinline__ float waveMax(float v) {
#pragma unroll
  for (int o = 32; o > 0; o >>= 1) v = fmaxf(v, __shfl_down(v, o));
  return v;
}
__device__ __forceinline__ float waveSum(float v) {
#pragma unroll
  for (int o = 32; o > 0; o >>= 1) v += __shfl_down(v, o);
  return v;
}

__global__ __launch_bounds__(1024) void softmax_f16_kernel(
    const f16* __restrict__ lg, float* __restrict__ out) {
  const f16x8* L = (const f16x8*)(lg + (size_t)blockIdx.x * V_DIM);
  float4* p4 = (float4*)(out + (size_t)blockIdx.x * V_DIM);
  const int t = threadIdx.x;
  __shared__ float sred[16];

  float4 v[8];
  float m = -1e30f;
#pragma unroll
  for (int j = 0; j < 4; ++j) {
    const int i = j * 1024 + t;        // f16x8 index, < 4000
    if (i < 4000) {
      const f16x8 h = L[i];
      v[2 * j].x     = (float)h[0]; v[2 * j].y     = (float)h[1];
      v[2 * j].z     = (float)h[2]; v[2 * j].w     = (float)h[3];
      v[2 * j + 1].x = (float)h[4]; v[2 * j + 1].y = (float)h[5];
      v[2 * j + 1].z = (float)h[6]; v[2 * j + 1].w = (float)h[7];
      m = fmaxf(m, fmaxf(fmaxf(v[2 * j].x, v[2 * j].y),
                         fmaxf(v[2 * j].z, v[2 * j].w)));
      m = fmaxf(m, fmaxf(fmaxf(v[2 * j + 1].x, v[2 * j + 1].y),
                         fmaxf(v[2 * j + 1].z, v[2 * j + 1].w)));
    }
  }
  m = waveMax(m);
  if ((t & 63) == 0) sred[t >> 6] = m;
  __syncthreads();
  float mb = sred[0];
#pragma unroll
  for (int k = 1; k < 16; ++k) mb = fmaxf(mb, sred[k]);
  __syncthreads();

  float s = 0.f;
#pragma unroll
  for (int j = 0; j < 8; ++j) {
    const int i = (j >> 1) * 1024 + t;
    if (i < 4000) {
      v[j].x = expf(v[j].x - mb);
      v[j].y = expf(v[j].y - mb);
      v[j].z = expf(v[j].z - mb);
      v[j].w = expf(v[j].w - mb);
      s += v[j].x + v[j].y + v[j].z + v[j].w;
    }
  }
  s = waveSum(s);
  if ((t & 63) == 0) sred[t >> 6] = s;
  __syncthreads();
  float sb = sred[0];
#pragma unroll
  for (int k = 1; k < 16; ++k) sb += sred[k];
  const float inv = 1.0f / sb;

#pragma unroll
  for (int j = 0; j < 4; ++j) {
    const int i = j * 1024 + t;
    if (i < 4000) {
      float4 a = v[2 * j], b = v[2 * j + 1];
      a.x *= inv; a.y *= inv; a.z *= inv; a.w *= inv;
      b.x *= inv; b.y *= inv; b.z *= inv; b.w *= inv;
      p4[2 * i] = a;
      p4[2 * i + 1] = b;
    }
  }
}

__global__ __launch_bounds__(1024) void softmax_reg_kernel(
    float* __restrict__ out) {
  float4* p4 = (float4*)(out + (size_t)blockIdx.x * V_DIM);
  const int t = threadIdx.x;
  __shared__ float sred[16];
  float4 v[8];
  float m = -1e30f;
#pragma unroll
  for (int j = 0; j < 8; ++j) {
    const int i = j * 1024 + t;
    if (i < 8000) {
      v[j] = p4[i];
      m = fmaxf(m, fmaxf(fmaxf(v[j].x, v[j].y), fmaxf(v[j].z, v[j].w)));
    }
  }
  m = waveMax(m);
  if ((t & 63) == 0) sred[t >> 6] = m;
  __syncthreads();
  float mb = sred[0];
#pragma unroll
  for (int k = 1; k < 16; ++k) mb = fmaxf(mb, sred[k]);
  __syncthreads();
  float s = 0.f;
#pragma unroll
  for (int j = 0; j < 8; ++j) {
    const int i = j * 1024 + t;
    if (i < 8000) {
      v[j].x = expf(v[j].x - mb);
      v[j].y = expf(v[j].y - mb);
      v[j].z = expf(v[j].z - mb);
      v[j].w = expf(v[j].w - mb);
      s += v[j].x + v[j].y + v[j].z + v[j].w;
    }
  }
  s = waveSum(s);
  if ((t & 63) == 0) sred[t >> 6] = s;
  __syncthreads();
  float sb = sred[0];
#pragma unroll
  for (int k = 1; k < 16; ++k) sb += sred[k];
  const float inv = 1.0f / sb;
#pragma unroll
  for (int j = 0; j < 8; ++j) {
    const int i = j * 1024 + t;
    if (i < 8000) {
      float4 o;
      o.x = v[j].x * inv; o.y = v[j].y * inv;
      o.z = v[j].z * inv; o.w = v[j].w * inv;
      p4[i] = o;
    }
  }
}

// ---------------------------------------------------------------------------
extern "C" void kernel_launch(void* const* d_in, const int* in_sizes, int n_in,
                              void* d_out, int out_size, void* d_ws, size_t ws_size,
                              hipStream_t stream) {
  const float* features = (const float*)d_in[0];
  const int*   captions = (const int*)d_in[1];
  const float* emb      = (const float*)d_in[3];
  const float* w_ih     = (const float*)d_in[4];
  const float* w_hh     = (const float*)d_in[5];
  const float* b_ih     = (const float*)d_in[6];
  const float* b_hh     = (const float*)d_in[7];
  const float* fc_w     = (const float*)d_in[8];
  const float* fc_b     = (const float*)d_in[9];
  float* out = (float*)d_out;

  // ---- d_ws layout ----
  char* ws = (char*)d_ws;
  unsigned* flags = (unsigned*)ws; ws += 512;                     // 128 flags
  f16* hsT = (f16*)ws;  ws += (size_t)21 * B_DIM * H_DIM * 2;     // 1.38 MB
  f16* w16 = (f16*)ws;  ws += (size_t)V_DIM * H_DIM * 2;          // 32.77 MB
  f16* logits16 = (f16*)ws;  // 81.92 MB if available
  const size_t ws_need_f16logits =
      ((char*)logits16 - (char*)d_ws) + (size_t)1280 * V_DIM * 2;  // ~116 MB
  const bool use_f16_logits = ws_size >= ws_need_f16logits;

  // ---- transient scratch in d_out (dead before final output writes) ----
  // P_T [21 slabs][2048][64] f32 = 11.0 MB
  float* PT    = out;
  f16*   x16   = (f16*)(out + 3000000);        // [1408][512] f16
  f16*   wih16 = (f16*)(out + 3400000);        // [2048][512] f16
  f16*   whh16 = (f16*)(out + 4000000);        // [2048][512] f16
  float* bsum  = out + 4600000;                // [2048] f32

  hipMemsetAsync(flags, 0, 512, stream);

  gather_x16_kernel<<<1408, 128, 0, stream>>>(features, captions, emb, x16);
  convert_w_kernel<<<1024, 256, 0, stream>>>(w_ih, wih16);
  convert_w_kernel<<<1024, 256, 0, stream>>>(w_hh, whh16);
  convert_w_kernel<<<16000, 256, 0, stream>>>(fc_w, w16);
  bias_sum_kernel<<<8, 256, 0, stream>>>(b_ih, b_hh, bsum);

  // proj -> P_T[t][gate-row][b]  (mode 2 epilogue)
  gemm16_kernel<<<dim3(16, 11), 256, 0, stream>>>(x16, wih16, bsum, PT, 0, 2);

  // all 21 LSTM steps, one kernel; coalesced h staging, W in registers
  lstm_persistent5<<<NBLK_LSTM, 256, 0, stream>>>(PT, whh16, hsT, flags);

  // FC A = hsT slabs 1..20 (rows t-major), C rows remapped to b-major
  const f16* Afc = hsT + (size_t)B_DIM * H_DIM;
  if (use_f16_logits) {
    gemm16_f16out_kernel<<<dim3(250, 10), 256, 0, stream>>>(Afc, w16, fc_b,
                                                            logits16);
    softmax_f16_kernel<<<1280, 1024, 0, stream>>>(logits16, out);
  } else {
    gemm16_kernel<<<dim3(250, 10), 256, 0, stream>>>(Afc, w16, fc_b, out,
                                                     32000, 1);
    softmax_reg_kernel<<<1280, 1024, 0, stream>>>(out);
  }
}

// Round 13
// 325.111 us; speedup vs baseline: 1.3118x; 1.0297x over previous
//
#include <hip/hip_runtime.h>
#include <cstdint>
#include <cstddef>

#define E_DIM 512
#define H_DIM 512
#define V_DIM 32000
#define B_DIM 64
#define T_DIM 20
#define NBLK 32        // LSTM blocks: 16 units each
#define PT_LDS 68      // pT row stride (f32)

typedef _Float16 f16;
typedef _Float16 f16x8 __attribute__((ext_vector_type(8)));
typedef _Float16 f16x4 __attribute__((ext_vector_type(4)));
typedef float    f32x4 __attribute__((ext_vector_type(4)));

__device__ __forceinline__ void async_lds16(void* lds, const void* g) {
  __builtin_amdgcn_global_load_lds(
      (const __attribute__((address_space(1))) uint32_t*)g,
      (__attribute__((address_space(3))) uint32_t*)lds, 16, 0, 0);
}

__device__ __forceinline__ float sigmoidf_(float x) {
  return 1.0f / (1.0f + expf(-x));
}

// Agent-coherent (cross-XCD) accesses — bypass non-coherent per-XCD L2s.
__device__ __forceinline__ f16x8 load_h8_coh(const f16* p) {
  union { unsigned long long u[2]; f16x8 v; } r;
  r.u[0] = __hip_atomic_load((const unsigned long long*)p,
                             __ATOMIC_RELAXED, __HIP_MEMORY_SCOPE_AGENT);
  r.u[1] = __hip_atomic_load((const unsigned long long*)(p + 4),
                             __ATOMIC_RELAXED, __HIP_MEMORY_SCOPE_AGENT);
  return r.v;
}
__device__ __forceinline__ void store_h4_coh(f16* p, f16x4 v) {
  union { f16x4 h; unsigned long long u; } cvt;
  cvt.h = v;
  __hip_atomic_store((unsigned long long*)p, cvt.u,
                     __ATOMIC_RELAXED, __HIP_MEMORY_SCOPE_AGENT);
}

// ---------------------------------------------------------------------------
// Gather x rows to fp16, T-MAJOR: x16[m'][512], m' = t*64 + b.
// ---------------------------------------------------------------------------
__global__ __launch_bounds__(128) void gather_x16_kernel(
    const float* __restrict__ features, const int* __restrict__ captions,
    const float* __restrict__ emb, f16* __restrict__ x16) {
  const int m = blockIdx.x;
  const int j = threadIdx.x;
  f16x4 r4 = {(f16)0.f, (f16)0.f, (f16)0.f, (f16)0.f};
  if (m < 1344) {
    const int b = m & 63;
    const int t = m >> 6;
    const float* src = (t == 0)
        ? features + (size_t)b * E_DIM
        : emb + (size_t)captions[b * T_DIM + (t - 1)] * E_DIM;
    const float4 v = ((const float4*)src)[j];
    r4.x = (f16)v.x; r4.y = (f16)v.y; r4.z = (f16)v.z; r4.w = (f16)v.w;
  }
  ((f16x4*)(x16 + (size_t)m * 512))[j] = r4;
}

__global__ __launch_bounds__(256) void convert_w_kernel(
    const float* __restrict__ w, f16* __restrict__ w16) {
  const int i = blockIdx.x * 256 + threadIdx.x;
  const float4 v = ((const float4*)w)[i];
  f16x4 r;
  r.x = (f16)v.x; r.y = (f16)v.y; r.z = (f16)v.z; r.w = (f16)v.w;
  ((f16x4*)w16)[i] = r;
}

__global__ __launch_bounds__(256) void bias_sum_kernel(
    const float* __restrict__ a, const float* __restrict__ b,
    float* __restrict__ o) {
  const int i = blockIdx.x * 256 + threadIdx.x;
  if (i < 2048) o[i] = a[i] + b[i];
}

// ---------------------------------------------------------------------------
// K=512 fp16 GEMM (B^T form). mode 0: plain; mode 1: FC row-remap;
// mode 2: proj P_T write off = (m>>6)*131072 + n*64 + (m&63).
// ---------------------------------------------------------------------------
__global__ __launch_bounds__(256) void gemm16_kernel(
    const f16* __restrict__ A, const f16* __restrict__ Bw,
    const float* __restrict__ bias, float* __restrict__ C, int ldc,
    int mode) {
  __shared__ f16 As[128 * 64];
  __shared__ f16 Bs[128 * 64];
  const int tid = threadIdx.x;
  const int lane = tid & 63;
  const int wid = tid >> 6;
  const int m0 = blockIdx.y * 128;
  const int n0 = blockIdx.x * 128;
  const int wm = (wid >> 1) * 64;
  const int wn = (wid & 1) * 64;

  f32x4 acc[4][4];
#pragma unroll
  for (int i = 0; i < 4; ++i)
#pragma unroll
    for (int j = 0; j < 4; ++j) {
      f32x4 z = {0.f, 0.f, 0.f, 0.f};
      acc[i][j] = z;
    }
  const int lr = lane & 15;
  const int lkb = (lane >> 4) * 8;

  for (int kt = 0; kt < 512; kt += 64) {
#pragma unroll
    for (int i = 0; i < 4; ++i) {
      const int off = i * 4096 + wid * 1024 + lane * 16;
      const int row = off >> 7;
      const int colh = (off & 127) >> 1;
      async_lds16((char*)As + i * 4096 + wid * 1024,
                  A + (size_t)(m0 + row) * 512 + kt + colh);
      async_lds16((char*)Bs + i * 4096 + wid * 1024,
                  Bw + (size_t)(n0 + row) * 512 + kt + colh);
    }
    __syncthreads();
#pragma unroll
    for (int ks = 0; ks < 2; ++ks) {
      f16x8 af[4], bf[4];
#pragma unroll
      for (int mi = 0; mi < 4; ++mi)
        af[mi] = *(const f16x8*)&As[(wm + mi * 16 + lr) * 64 + ks * 32 + lkb];
#pragma unroll
      for (int ni = 0; ni < 4; ++ni)
        bf[ni] = *(const f16x8*)&Bs[(wn + ni * 16 + lr) * 64 + ks * 32 + lkb];
#pragma unroll
      for (int mi = 0; mi < 4; ++mi)
#pragma unroll
        for (int ni = 0; ni < 4; ++ni)
          acc[mi][ni] = __builtin_amdgcn_mfma_f32_16x16x32_f16(
              af[mi], bf[ni], acc[mi][ni], 0, 0, 0);
    }
    __syncthreads();
  }

#pragma unroll
  for (int mi = 0; mi < 4; ++mi) {
    const int mbase = m0 + wm + mi * 16 + (lane >> 4) * 4;
#pragma unroll
    for (int ni = 0; ni < 4; ++ni) {
      const int n = n0 + wn + ni * 16 + lr;
      const float bv = bias[n];
#pragma unroll
      for (int r = 0; r < 4; ++r) {
        const int mr = mbase + r;
        size_t off;
        if (mode == 2)
          off = (size_t)(mr >> 6) * (2048 * 64) + (size_t)n * 64 + (mr & 63);
        else if (mode == 1)
          off = (size_t)((mr & 63) * 20 + (mr >> 6)) * ldc + n;
        else
          off = (size_t)mr * ldc + n;
        C[off] = acc[mi][ni][r] + bv;
      }
    }
  }
}

// Same GEMM, f16 C output, FC-only (ldc=32000, rows remapped to b-major).
__global__ __launch_bounds__(256) void gemm16_f16out_kernel(
    const f16* __restrict__ A, const f16* __restrict__ Bw,
    const float* __restrict__ bias, f16* __restrict__ C16) {
  __shared__ f16 As[128 * 64];
  __shared__ f16 Bs[128 * 64];
  const int tid = threadIdx.x;
  const int lane = tid & 63;
  const int wid = tid >> 6;
  const int m0 = blockIdx.y * 128;
  const int n0 = blockIdx.x * 128;
  const int wm = (wid >> 1) * 64;
  const int wn = (wid & 1) * 64;

  f32x4 acc[4][4];
#pragma unroll
  for (int i = 0; i < 4; ++i)
#pragma unroll
    for (int j = 0; j < 4; ++j) {
      f32x4 z = {0.f, 0.f, 0.f, 0.f};
      acc[i][j] = z;
    }
  const int lr = lane & 15;
  const int lkb = (lane >> 4) * 8;

  for (int kt = 0; kt < 512; kt += 64) {
#pragma unroll
    for (int i = 0; i < 4; ++i) {
      const int off = i * 4096 + wid * 1024 + lane * 16;
      const int row = off >> 7;
      const int colh = (off & 127) >> 1;
      async_lds16((char*)As + i * 4096 + wid * 1024,
                  A + (size_t)(m0 + row) * 512 + kt + colh);
      async_lds16((char*)Bs + i * 4096 + wid * 1024,
                  Bw + (size_t)(n0 + row) * 512 + kt + colh);
    }
    __syncthreads();
#pragma unroll
    for (int ks = 0; ks < 2; ++ks) {
      f16x8 af[4], bf[4];
#pragma unroll
      for (int mi = 0; mi < 4; ++mi)
        af[mi] = *(const f16x8*)&As[(wm + mi * 16 + lr) * 64 + ks * 32 + lkb];
#pragma unroll
      for (int ni = 0; ni < 4; ++ni)
        bf[ni] = *(const f16x8*)&Bs[(wn + ni * 16 + lr) * 64 + ks * 32 + lkb];
#pragma unroll
      for (int mi = 0; mi < 4; ++mi)
#pragma unroll
        for (int ni = 0; ni < 4; ++ni)
          acc[mi][ni] = __builtin_amdgcn_mfma_f32_16x16x32_f16(
              af[mi], bf[ni], acc[mi][ni], 0, 0, 0);
    }
    __syncthreads();
  }

#pragma unroll
  for (int mi = 0; mi < 4; ++mi) {
    const int mbase = m0 + wm + mi * 16 + (lane >> 4) * 4;
#pragma unroll
    for (int ni = 0; ni < 4; ++ni) {
      const int n = n0 + wn + ni * 16 + lr;
      const float bv = bias[n];
#pragma unroll
      for (int r = 0; r < 4; ++r) {
        const int mr = mbase + r;
        const int orow = (mr & 63) * 20 + (mr >> 6);
        C16[(size_t)orow * 32000 + n] = (f16)(acc[mi][ni][r] + bv);
      }
    }
  }
}

// ---------------------------------------------------------------------------
// Persistent LSTM v6: 32 blocks x 256 thr; block owns 16 units (64 gate
// rows). De-contention vs v5: 4x fewer barrier participants and coherent
// reads (2MB/step); h stores routed via LDS -> coalesced 8B chunks (16x
// fewer store transactions); flags padded to 64B/block, wave0-only poll;
// P step-slice prefetched into LDS during the barrier wait.
// Wave w: units u0+w*4..+3, gate rows grow=(fr>>2)*512+u0+w*4+(fr&3);
// computes all 4 b-tiles (mi). Elementwise distributed on ALL 64 lanes via
// per-tile shfl_xor + compile-time selects (lane's tile = fr>>2).
// ---------------------------------------------------------------------------
__global__ __launch_bounds__(256, 1) void lstm_persistent6(
    const float* __restrict__ PT, const f16* __restrict__ Whh,
    f16* __restrict__ hsT, unsigned* __restrict__ flags) {
  __shared__ f16 hS[64 * 520];            // 66.5 KB staged h (block-wide)
  __shared__ float pT[64 * PT_LDS];       // 17.4 KB step P slice
  __shared__ f16 hS2[64 * 16];            // 2 KB outgoing h
  const int tid = threadIdx.x;
  const int lane = tid & 63;
  const int w = tid >> 6;
  const int u0 = blockIdx.x * 16;
  const int fr = lane & 15;
  const int fq = lane >> 4;
  const int q = fr >> 2;                  // lane's gate / b-tile
  const int jw = fr & 3;                  // unit within wave
  const int grow = q * 512 + u0 + w * 4 + jw;

  // W fragments -> VGPRs once (scatter paid once, reused 20 steps)
  f16x8 bW[16];
  {
    const f16* brow = Whh + (size_t)grow * 512;
#pragma unroll
    for (int kk = 0; kk < 16; ++kk)
      bW[kk] = *(const f16x8*)&brow[kk * 32 + fq * 8];
  }

  // prologue: stage P slice for t=0 (coalesced 256B rows from L2)
  for (int i = tid; i < 64 * 16; i += 256) {
    const int rr = i >> 4;                // block gate row: g*16 + ul
    const int q4 = i & 15;
    const int g = rr >> 4, ul = rr & 15;
    const float4 v =
        *(const float4*)&PT[((size_t)(g * 512 + u0 + ul)) * 64 + q4 * 4];
    *(float4*)&pT[rr * PT_LDS + q4 * 4] = v;
  }

  float cr[4] = {0.f, 0.f, 0.f, 0.f};  // c[b=q*16+fq*4+r][u0+w*4+jw]

  for (int t = 0; t <= T_DIM; ++t) {
    if (t > 0) {
      // stage h: wave w loads rows w*16..+15 (contiguous, lane-coalesced)
      const f16* src = hsT + (size_t)(t - 1) * (64 * 512)
                           + (size_t)(w * 16) * 512;
      f16x8 hrow[16];
#pragma unroll
      for (int j = 0; j < 16; ++j)
        hrow[j] = load_h8_coh(src + (size_t)j * 512 + lane * 8);
#pragma unroll
      for (int j = 0; j < 16; ++j)
        *(f16x8*)&hS[(w * 16 + j) * 520 + lane * 8] = hrow[j];
    }
    __syncthreads();   // publishes hS (and pT from prefetch/prologue)

    f32x4 acc[4];
#pragma unroll
    for (int mi = 0; mi < 4; ++mi) {
      f32x4 z = {0.f, 0.f, 0.f, 0.f};
      acc[mi] = z;
    }
    if (t > 0) {
#pragma unroll
      for (int mi = 0; mi < 4; ++mi) {
        f16x8 a[16];
#pragma unroll
        for (int kk = 0; kk < 16; ++kk)
          a[kk] = *(const f16x8*)&hS[(mi * 16 + fr) * 520 + kk * 32 + fq * 8];
#pragma unroll
        for (int kk = 0; kk < 16; ++kk)
          acc[mi] = __builtin_amdgcn_mfma_f32_16x16x32_f16(a[kk], bW[kk],
                                                           acc[mi], 0, 0, 0);
      }
    }
    // P-add: lane's gate row rr_b = q*16 + w*4 + jw
    const int prow = (q * 16 + w * 4 + jw) * PT_LDS;
#pragma unroll
    for (int mi = 0; mi < 4; ++mi)
#pragma unroll
      for (int r = 0; r < 4; ++r)
        acc[mi][r] += pT[prow + mi * 16 + fq * 4 + r];

    // elementwise, all 64 lanes: lane processes tile mi == q
#pragma unroll
    for (int r = 0; r < 4; ++r) {
      const float y0 = acc[0][r], y1 = acc[1][r], y2 = acc[2][r],
                  y3 = acc[3][r];
      const float f0 = __shfl_xor(y0, 4),  f1 = __shfl_xor(y1, 4),
                  f2 = __shfl_xor(y2, 4),  f3 = __shfl_xor(y3, 4);
      const float g0 = __shfl_xor(y0, 8),  g1 = __shfl_xor(y1, 8),
                  g2 = __shfl_xor(y2, 8),  g3 = __shfl_xor(y3, 8);
      const float o0 = __shfl_xor(y0, 12), o1 = __shfl_xor(y1, 12),
                  o2 = __shfl_xor(y2, 12), o3 = __shfl_xor(y3, 12);
      const float x  = q == 0 ? y0 : q == 1 ? y1 : q == 2 ? y2 : y3;
      const float xf = q == 0 ? f0 : q == 1 ? f1 : q == 2 ? f2 : f3;
      const float xg = q == 0 ? g0 : q == 1 ? g1 : q == 2 ? g2 : g3;
      const float xo = q == 0 ? o0 : q == 1 ? o1 : q == 2 ? o2 : o3;
      // gate permutation by q (x = own gate q; partners at q^1,q^2,q^3)
      const float gi = q == 0 ? x  : q == 1 ? xf : q == 2 ? xg : xo;
      const float gf = q == 0 ? xf : q == 1 ? x  : q == 2 ? xo : xg;
      const float gg = q == 0 ? xg : q == 1 ? xo : q == 2 ? x  : xf;
      const float go = q == 0 ? xo : q == 1 ? xg : q == 2 ? xf : x;
      const float si = sigmoidf_(gi);
      const float sf = sigmoidf_(gf);
      const float tg = tanhf(gg);
      const float so = sigmoidf_(go);
      const float cn = sf * cr[r] + si * tg;
      cr[r] = cn;
      const float hn = so * tanhf(cn);
      const int b = q * 16 + fq * 4 + r;
      hS2[b * 16 + w * 4 + jw] = (f16)hn;
    }
    __syncthreads();

    // coalesced coherent store: block's [64 b][16 u] region in 8B chunks
    {
      f16* slab = hsT + (size_t)t * (64 * 512);
      const int row = tid >> 2;
      const int c4 = tid & 3;
      const f16x4 v = *(const f16x4*)&hS2[row * 16 + c4 * 4];
      store_h4_coh(slab + (size_t)row * 512 + u0 + c4 * 4, v);
    }

    if (t < T_DIM) {
      // prefetch next step's P slice into pT (overlaps barrier wait)
      for (int i = tid; i < 64 * 16; i += 256) {
        const int rr = i >> 4;
        const int q4 = i & 15;
        const int g = rr >> 4, ul = rr & 15;
        const float4 v = *(const float4*)
            &PT[((size_t)(t + 1) * 2048 + g * 512 + u0 + ul) * 64 + q4 * 4];
        *(float4*)&pT[rr * PT_LDS + q4 * 4] = v;
      }
      asm volatile("s_waitcnt vmcnt(0)" ::: "memory");
      __syncthreads();
      if (tid == 0)
        __hip_atomic_store(&flags[blockIdx.x * 16], (unsigned)(t + 1),
                           __ATOMIC_RELAXED, __HIP_MEMORY_SCOPE_AGENT);
      if (tid < NBLK) {
        while (__hip_atomic_load(&flags[tid * 16], __ATOMIC_RELAXED,
                                 __HIP_MEMORY_SCOPE_AGENT) < (unsigned)(t + 1))
          __builtin_amdgcn_s_sleep(3);
      }
      __syncthreads();
    }
  }
}

// ---------------------------------------------------------------------------
// Softmax over V=32000, row in registers (1024 thr).
// ---------------------------------------------------------------------------
__device__ __forceinline__ float waveMax(float v) {
#pragma unroll
  for (int o = 32; o > 0; o >>= 1) v = fmaxf(v, __shfl_down(v, o));
  return v;
}
__device__ __forceinline__ float waveSum(float v) {
#pragma unroll
  for (int o = 32; o > 0; o >>= 1) v += __shfl_down(v, o);
  return v;
}

__global__ __launch_bounds__(1024) void softmax_f16_kernel(
    const f16* __restrict__ lg, float* __restrict__ out) {
  const f16x8* L = (const f16x8*)(lg + (size_t)blockIdx.x * V_DIM);
  float4* p4 = (float4*)(out + (size_t)blockIdx.x * V_DIM);
  const int t = threadIdx.x;
  __shared__ float sred[16];

  float4 v[8];
  float m = -1e30f;
#pragma unroll
  for (int j = 0; j < 4; ++j) {
    const int i = j * 1024 + t;
    if (i < 4000) {
      const f16x8 h = L[i];
      v[2 * j].x     = (float)h[0]; v[2 * j].y     = (float)h[1];
      v[2 * j].z     = (float)h[2]; v[2 * j].w     = (float)h[3];
      v[2 * j + 1].x = (float)h[4]; v[2 * j + 1].y = (float)h[5];
      v[2 * j + 1].z = (float)h[6]; v[2 * j + 1].w = (float)h[7];
      m = fmaxf(m, fmaxf(fmaxf(v[2 * j].x, v[2 * j].y),
                         fmaxf(v[2 * j].z, v[2 * j].w)));
      m = fmaxf(m, fmaxf(fmaxf(v[2 * j + 1].x, v[2 * j + 1].y),
                         fmaxf(v[2 * j + 1].z, v[2 * j + 1].w)));
    }
  }
  m = waveMax(m);
  if ((t & 63) == 0) sred[t >> 6] = m;
  __syncthreads();
  float mb = sred[0];
#pragma unroll
  for (int k = 1; k < 16; ++k) mb = fmaxf(mb, sred[k]);
  __syncthreads();

  float s = 0.f;
#pragma unroll
  for (int j = 0; j < 8; ++j) {
    const int i = (j >> 1) * 1024 + t;
    if (i < 4000) {
      v[j].x = expf(v[j].x - mb);
      v[j].y = expf(v[j].y - mb);
      v[j].z = expf(v[j].z - mb);
      v[j].w = expf(v[j].w - mb);
      s += v[j].x + v[j].y + v[j].z + v[j].w;
    }
  }
  s = waveSum(s);
  if ((t & 63) == 0) sred[t >> 6] = s;
  __syncthreads();
  float sb = sred[0];
#pragma unroll
  for (int k = 1; k < 16; ++k) sb += sred[k];
  const float inv = 1.0f / sb;

#pragma unroll
  for (int j = 0; j < 4; ++j) {
    const int i = j * 1024 + t;
    if (i < 4000) {
      float4 a = v[2 * j], b = v[2 * j + 1];
      a.x *= inv; a.y *= inv; a.z *= inv; a.w *= inv;
      b.x *= inv; b.y *= inv; b.z *= inv; b.w *= inv;
      p4[2 * i] = a;
      p4[2 * i + 1] = b;
    }
  }
}

__global__ __launch_bounds__(1024) void softmax_reg_kernel(
    float* __restrict__ out) {
  float4* p4 = (float4*)(out + (size_t)blockIdx.x * V_DIM);
  const int t = threadIdx.x;
  __shared__ float sred[16];
  float4 v[8];
  float m = -1e30f;
#pragma unroll
  for (int j = 0; j < 8; ++j) {
    const int i = j * 1024 + t;
    if (i < 8000) {
      v[j] = p4[i];
      m = fmaxf(m, fmaxf(fmaxf(v[j].x, v[j].y), fmaxf(v[j].z, v[j].w)));
    }
  }
  m = waveMax(m);
  if ((t & 63) == 0) sred[t >> 6] = m;
  __syncthreads();
  float mb = sred[0];
#pragma unroll
  for (int k = 1; k < 16; ++k) mb = fmaxf(mb, sred[k]);
  __syncthreads();
  float s = 0.f;
#pragma unroll
  for (int j = 0; j < 8; ++j) {
    const int i = j * 1024 + t;
    if (i < 8000) {
      v[j].x = expf(v[j].x - mb);
      v[j].y = expf(v[j].y - mb);
      v[j].z = expf(v[j].z - mb);
      v[j].w = expf(v[j].w - mb);
      s += v[j].x + v[j].y + v[j].z + v[j].w;
    }
  }
  s = waveSum(s);
  if ((t & 63) == 0) sred[t >> 6] = s;
  __syncthreads();
  float sb = sred[0];
#pragma unroll
  for (int k = 1; k < 16; ++k) sb += sred[k];
  const float inv = 1.0f / sb;
#pragma unroll
  for (int j = 0; j < 8; ++j) {
    const int i = j * 1024 + t;
    if (i < 8000) {
      float4 o;
      o.x = v[j].x * inv; o.y = v[j].y * inv;
      o.z = v[j].z * inv; o.w = v[j].w * inv;
      p4[i] = o;
    }
  }
}

// ---------------------------------------------------------------------------
extern "C" void kernel_launch(void* const* d_in, const int* in_sizes, int n_in,
                              void* d_out, int out_size, void* d_ws, size_t ws_size,
                              hipStream_t stream) {
  const float* features = (const float*)d_in[0];
  const int*   captions = (const int*)d_in[1];
  const float* emb      = (const float*)d_in[3];
  const float* w_ih     = (const float*)d_in[4];
  const float* w_hh     = (const float*)d_in[5];
  const float* b_ih     = (const float*)d_in[6];
  const float* b_hh     = (const float*)d_in[7];
  const float* fc_w     = (const float*)d_in[8];
  const float* fc_b     = (const float*)d_in[9];
  float* out = (float*)d_out;

  // ---- d_ws layout ----
  char* ws = (char*)d_ws;
  unsigned* flags = (unsigned*)ws; ws += 2048;                    // 32 x 64B
  f16* hsT = (f16*)ws;  ws += (size_t)21 * B_DIM * H_DIM * 2;     // 1.38 MB
  f16* w16 = (f16*)ws;  ws += (size_t)V_DIM * H_DIM * 2;          // 32.77 MB
  f16* logits16 = (f16*)ws;  // 81.92 MB if available
  const size_t ws_need_f16logits =
      ((char*)logits16 - (char*)d_ws) + (size_t)1280 * V_DIM * 2;  // ~116 MB
  const bool use_f16_logits = ws_size >= ws_need_f16logits;

  // ---- transient scratch in d_out (dead before final output writes) ----
  float* PT    = out;                          // [21][2048][64] f32, 11 MB
  f16*   x16   = (f16*)(out + 3000000);        // [1408][512] f16
  f16*   wih16 = (f16*)(out + 3400000);        // [2048][512] f16
  f16*   whh16 = (f16*)(out + 4000000);        // [2048][512] f16
  float* bsum  = out + 4600000;                // [2048] f32

  hipMemsetAsync(flags, 0, 2048, stream);

  gather_x16_kernel<<<1408, 128, 0, stream>>>(features, captions, emb, x16);
  convert_w_kernel<<<1024, 256, 0, stream>>>(w_ih, wih16);
  convert_w_kernel<<<1024, 256, 0, stream>>>(w_hh, whh16);
  convert_w_kernel<<<16000, 256, 0, stream>>>(fc_w, w16);
  bias_sum_kernel<<<8, 256, 0, stream>>>(b_ih, b_hh, bsum);

  // proj -> P_T[t][gate-row][b]  (mode 2 epilogue)
  gemm16_kernel<<<dim3(16, 11), 256, 0, stream>>>(x16, wih16, bsum, PT, 0, 2);

  // all 21 LSTM steps, one kernel, de-contended sync
  lstm_persistent6<<<NBLK, 256, 0, stream>>>(PT, whh16, hsT, flags);

  // FC A = hsT slabs 1..20 (rows t-major), C rows remapped to b-major
  const f16* Afc = hsT + (size_t)B_DIM * H_DIM;
  if (use_f16_logits) {
    gemm16_f16out_kernel<<<dim3(250, 10), 256, 0, stream>>>(Afc, w16, fc_b,
                                                            logits16);
    softmax_f16_kernel<<<1280, 1024, 0, stream>>>(logits16, out);
  } else {
    gemm16_kernel<<<dim3(250, 10), 256, 0, stream>>>(Afc, w16, fc_b, out,
                                                     32000, 1);
    softmax_reg_kernel<<<1280, 1024, 0, stream>>>(out);
  }
}

// Round 14
// 308.241 us; speedup vs baseline: 1.3836x; 1.0547x over previous
//
#include <hip/hip_runtime.h>
#include <cstdint>
#include <cstddef>

#define E_DIM 512
#define H_DIM 512
#define V_DIM 32000
#define B_DIM 64
#define T_DIM 20
#define NBLK 32        // LSTM blocks (16 units each); blocks 32.. do convert
#define NBLK_TOT 256
#define PT_LDS 68      // pT row stride (f32)
#define HS_STR 532     // hS row stride (f16): 266 dw == 10 mod 32 -> 2-way

typedef _Float16 f16;
typedef _Float16 f16x8 __attribute__((ext_vector_type(8)));
typedef _Float16 f16x4 __attribute__((ext_vector_type(4)));
typedef float    f32x4 __attribute__((ext_vector_type(4)));

__device__ __forceinline__ void async_lds16(void* lds, const void* g) {
  __builtin_amdgcn_global_load_lds(
      (const __attribute__((address_space(1))) uint32_t*)g,
      (__attribute__((address_space(3))) uint32_t*)lds, 16, 0, 0);
}

__device__ __forceinline__ float sigmoidf_(float x) {
  return 1.0f / (1.0f + expf(-x));
}

// Agent-coherent (cross-XCD) accesses — bypass non-coherent per-XCD L2s.
__device__ __forceinline__ f16x8 load_h8_coh(const f16* p) {
  union { unsigned long long u[2]; f16x8 v; } r;
  r.u[0] = __hip_atomic_load((const unsigned long long*)p,
                             __ATOMIC_RELAXED, __HIP_MEMORY_SCOPE_AGENT);
  r.u[1] = __hip_atomic_load((const unsigned long long*)(p + 4),
                             __ATOMIC_RELAXED, __HIP_MEMORY_SCOPE_AGENT);
  return r.v;
}
__device__ __forceinline__ void store_h4_coh(f16* p, f16x4 v) {
  union { f16x4 h; unsigned long long u; } cvt;
  cvt.h = v;
  __hip_atomic_store((unsigned long long*)p, cvt.u,
                     __ATOMIC_RELAXED, __HIP_MEMORY_SCOPE_AGENT);
}

// ---------------------------------------------------------------------------
// Gather x rows to fp16, T-MAJOR: x16[m'][512], m' = t*64 + b.
// ---------------------------------------------------------------------------
__global__ __launch_bounds__(128) void gather_x16_kernel(
    const float* __restrict__ features, const int* __restrict__ captions,
    const float* __restrict__ emb, f16* __restrict__ x16) {
  const int m = blockIdx.x;
  const int j = threadIdx.x;
  f16x4 r4 = {(f16)0.f, (f16)0.f, (f16)0.f, (f16)0.f};
  if (m < 1344) {
    const int b = m & 63;
    const int t = m >> 6;
    const float* src = (t == 0)
        ? features + (size_t)b * E_DIM
        : emb + (size_t)captions[b * T_DIM + (t - 1)] * E_DIM;
    const float4 v = ((const float4*)src)[j];
    r4.x = (f16)v.x; r4.y = (f16)v.y; r4.z = (f16)v.z; r4.w = (f16)v.w;
  }
  ((f16x4*)(x16 + (size_t)m * 512))[j] = r4;
}

__global__ __launch_bounds__(256) void convert_w_kernel(
    const float* __restrict__ w, f16* __restrict__ w16) {
  const int i = blockIdx.x * 256 + threadIdx.x;
  const float4 v = ((const float4*)w)[i];
  f16x4 r;
  r.x = (f16)v.x; r.y = (f16)v.y; r.z = (f16)v.z; r.w = (f16)v.w;
  ((f16x4*)w16)[i] = r;
}

__global__ __launch_bounds__(256) void bias_sum_kernel(
    const float* __restrict__ a, const float* __restrict__ b,
    float* __restrict__ o) {
  const int i = blockIdx.x * 256 + threadIdx.x;
  if (i < 2048) o[i] = a[i] + b[i];
}

// ---------------------------------------------------------------------------
// K=512 fp16 GEMM (B^T form). mode 0: plain; mode 1: FC row-remap;
// mode 2: proj P_T write off = (m>>6)*131072 + n*64 + (m&63).
// ---------------------------------------------------------------------------
__global__ __launch_bounds__(256) void gemm16_kernel(
    const f16* __restrict__ A, const f16* __restrict__ Bw,
    const float* __restrict__ bias, float* __restrict__ C, int ldc,
    int mode) {
  __shared__ f16 As[128 * 64];
  __shared__ f16 Bs[128 * 64];
  const int tid = threadIdx.x;
  const int lane = tid & 63;
  const int wid = tid >> 6;
  const int m0 = blockIdx.y * 128;
  const int n0 = blockIdx.x * 128;
  const int wm = (wid >> 1) * 64;
  const int wn = (wid & 1) * 64;

  f32x4 acc[4][4];
#pragma unroll
  for (int i = 0; i < 4; ++i)
#pragma unroll
    for (int j = 0; j < 4; ++j) {
      f32x4 z = {0.f, 0.f, 0.f, 0.f};
      acc[i][j] = z;
    }
  const int lr = lane & 15;
  const int lkb = (lane >> 4) * 8;

  for (int kt = 0; kt < 512; kt += 64) {
#pragma unroll
    for (int i = 0; i < 4; ++i) {
      const int off = i * 4096 + wid * 1024 + lane * 16;
      const int row = off >> 7;
      const int colh = (off & 127) >> 1;
      async_lds16((char*)As + i * 4096 + wid * 1024,
                  A + (size_t)(m0 + row) * 512 + kt + colh);
      async_lds16((char*)Bs + i * 4096 + wid * 1024,
                  Bw + (size_t)(n0 + row) * 512 + kt + colh);
    }
    __syncthreads();
#pragma unroll
    for (int ks = 0; ks < 2; ++ks) {
      f16x8 af[4], bf[4];
#pragma unroll
      for (int mi = 0; mi < 4; ++mi)
        af[mi] = *(const f16x8*)&As[(wm + mi * 16 + lr) * 64 + ks * 32 + lkb];
#pragma unroll
      for (int ni = 0; ni < 4; ++ni)
        bf[ni] = *(const f16x8*)&Bs[(wn + ni * 16 + lr) * 64 + ks * 32 + lkb];
#pragma unroll
      for (int mi = 0; mi < 4; ++mi)
#pragma unroll
        for (int ni = 0; ni < 4; ++ni)
          acc[mi][ni] = __builtin_amdgcn_mfma_f32_16x16x32_f16(
              af[mi], bf[ni], acc[mi][ni], 0, 0, 0);
    }
    __syncthreads();
  }

#pragma unroll
  for (int mi = 0; mi < 4; ++mi) {
    const int mbase = m0 + wm + mi * 16 + (lane >> 4) * 4;
#pragma unroll
    for (int ni = 0; ni < 4; ++ni) {
      const int n = n0 + wn + ni * 16 + lr;
      const float bv = bias[n];
#pragma unroll
      for (int r = 0; r < 4; ++r) {
        const int mr = mbase + r;
        size_t off;
        if (mode == 2)
          off = (size_t)(mr >> 6) * (2048 * 64) + (size_t)n * 64 + (mr & 63);
        else if (mode == 1)
          off = (size_t)((mr & 63) * 20 + (mr >> 6)) * ldc + n;
        else
          off = (size_t)mr * ldc + n;
        C[off] = acc[mi][ni][r] + bv;
      }
    }
  }
}

// Same GEMM, f16 C output, FC-only (ldc=32000, rows remapped to b-major).
__global__ __launch_bounds__(256) void gemm16_f16out_kernel(
    const f16* __restrict__ A, const f16* __restrict__ Bw,
    const float* __restrict__ bias, f16* __restrict__ C16) {
  __shared__ f16 As[128 * 64];
  __shared__ f16 Bs[128 * 64];
  const int tid = threadIdx.x;
  const int lane = tid & 63;
  const int wid = tid >> 6;
  const int m0 = blockIdx.y * 128;
  const int n0 = blockIdx.x * 128;
  const int wm = (wid >> 1) * 64;
  const int wn = (wid & 1) * 64;

  f32x4 acc[4][4];
#pragma unroll
  for (int i = 0; i < 4; ++i)
#pragma unroll
    for (int j = 0; j < 4; ++j) {
      f32x4 z = {0.f, 0.f, 0.f, 0.f};
      acc[i][j] = z;
    }
  const int lr = lane & 15;
  const int lkb = (lane >> 4) * 8;

  for (int kt = 0; kt < 512; kt += 64) {
#pragma unroll
    for (int i = 0; i < 4; ++i) {
      const int off = i * 4096 + wid * 1024 + lane * 16;
      const int row = off >> 7;
      const int colh = (off & 127) >> 1;
      async_lds16((char*)As + i * 4096 + wid * 1024,
                  A + (size_t)(m0 + row) * 512 + kt + colh);
      async_lds16((char*)Bs + i * 4096 + wid * 1024,
                  Bw + (size_t)(n0 + row) * 512 + kt + colh);
    }
    __syncthreads();
#pragma unroll
    for (int ks = 0; ks < 2; ++ks) {
      f16x8 af[4], bf[4];
#pragma unroll
      for (int mi = 0; mi < 4; ++mi)
        af[mi] = *(const f16x8*)&As[(wm + mi * 16 + lr) * 64 + ks * 32 + lkb];
#pragma unroll
      for (int ni = 0; ni < 4; ++ni)
        bf[ni] = *(const f16x8*)&Bs[(wn + ni * 16 + lr) * 64 + ks * 32 + lkb];
#pragma unroll
      for (int mi = 0; mi < 4; ++mi)
#pragma unroll
        for (int ni = 0; ni < 4; ++ni)
          acc[mi][ni] = __builtin_amdgcn_mfma_f32_16x16x32_f16(
              af[mi], bf[ni], acc[mi][ni], 0, 0, 0);
    }
    __syncthreads();
  }

#pragma unroll
  for (int mi = 0; mi < 4; ++mi) {
    const int mbase = m0 + wm + mi * 16 + (lane >> 4) * 4;
#pragma unroll
    for (int ni = 0; ni < 4; ++ni) {
      const int n = n0 + wn + ni * 16 + lr;
      const float bv = bias[n];
#pragma unroll
      for (int r = 0; r < 4; ++r) {
        const int mr = mbase + r;
        const int orow = (mr & 63) * 20 + (mr >> 6);
        C16[(size_t)orow * 32000 + n] = (f16)(acc[mi][ni][r] + bv);
      }
    }
  }
}

// ---------------------------------------------------------------------------
// Persistent LSTM v7 (fused): blocks 0..31 run the 21-step LSTM (as v6, with
// hS stride 532 -> 2-way bank aliasing instead of 8-way); blocks 32..255 run
// the fc_w f32->f16 convert on otherwise-idle CUs (no dependency on LSTM).
// 256 blocks x 87.5KB LDS = 1 block/CU -> all co-resident; LSTM co-residency
// preserved. Convert is pure BW (96MB over the LSTM's ~130us window).
// ---------------------------------------------------------------------------
__global__ __launch_bounds__(256, 1) void lstm_persistent7(
    const float* __restrict__ PT, const f16* __restrict__ Whh,
    f16* __restrict__ hsT, unsigned* __restrict__ flags,
    const float* __restrict__ fcw, f16* __restrict__ w16) {
  __shared__ f16 hS[64 * HS_STR];         // 68.1 KB staged h
  __shared__ float pT[64 * PT_LDS];       // 17.4 KB step P slice
  __shared__ f16 hS2[64 * 16];            // 2 KB outgoing h
  const int tid = threadIdx.x;

  if (blockIdx.x >= NBLK) {
    // ---- convert lane: w16 = (f16)fc_w, grid-stride over 4.096M float4 ----
    const int g0 = (blockIdx.x - NBLK) * 256 + tid;
    for (int i = g0; i < 4096000; i += (NBLK_TOT - NBLK) * 256) {
      const float4 v = ((const float4*)fcw)[i];
      f16x4 r;
      r.x = (f16)v.x; r.y = (f16)v.y; r.z = (f16)v.z; r.w = (f16)v.w;
      ((f16x4*)w16)[i] = r;
    }
    return;
  }

  const int lane = tid & 63;
  const int w = tid >> 6;
  const int u0 = blockIdx.x * 16;
  const int fr = lane & 15;
  const int fq = lane >> 4;
  const int q = fr >> 2;                  // lane's gate / b-tile
  const int jw = fr & 3;                  // unit within wave
  const int grow = q * 512 + u0 + w * 4 + jw;

  // W fragments -> VGPRs once (scatter paid once, reused 20 steps)
  f16x8 bW[16];
  {
    const f16* brow = Whh + (size_t)grow * 512;
#pragma unroll
    for (int kk = 0; kk < 16; ++kk)
      bW[kk] = *(const f16x8*)&brow[kk * 32 + fq * 8];
  }

  // prologue: stage P slice for t=0 (coalesced 256B rows from L2)
  for (int i = tid; i < 64 * 16; i += 256) {
    const int rr = i >> 4;                // block gate row: g*16 + ul
    const int q4 = i & 15;
    const int g = rr >> 4, ul = rr & 15;
    const float4 v =
        *(const float4*)&PT[((size_t)(g * 512 + u0 + ul)) * 64 + q4 * 4];
    *(float4*)&pT[rr * PT_LDS + q4 * 4] = v;
  }

  float cr[4] = {0.f, 0.f, 0.f, 0.f};  // c[b=q*16+fq*4+r][u0+w*4+jw]

  for (int t = 0; t <= T_DIM; ++t) {
    if (t > 0) {
      // stage h: wave w loads rows w*16..+15 (contiguous, lane-coalesced)
      const f16* src = hsT + (size_t)(t - 1) * (64 * 512)
                           + (size_t)(w * 16) * 512;
      f16x8 hrow[16];
#pragma unroll
      for (int j = 0; j < 16; ++j)
        hrow[j] = load_h8_coh(src + (size_t)j * 512 + lane * 8);
#pragma unroll
      for (int j = 0; j < 16; ++j)
        *(f16x8*)&hS[(w * 16 + j) * HS_STR + lane * 8] = hrow[j];
    }
    __syncthreads();   // publishes hS (and pT from prefetch/prologue)

    f32x4 acc[4];
#pragma unroll
    for (int mi = 0; mi < 4; ++mi) {
      f32x4 z = {0.f, 0.f, 0.f, 0.f};
      acc[mi] = z;
    }
    if (t > 0) {
#pragma unroll
      for (int mi = 0; mi < 4; ++mi) {
        f16x8 a[16];
#pragma unroll
        for (int kk = 0; kk < 16; ++kk)
          a[kk] =
              *(const f16x8*)&hS[(mi * 16 + fr) * HS_STR + kk * 32 + fq * 8];
#pragma unroll
        for (int kk = 0; kk < 16; ++kk)
          acc[mi] = __builtin_amdgcn_mfma_f32_16x16x32_f16(a[kk], bW[kk],
                                                           acc[mi], 0, 0, 0);
      }
    }
    // P-add: lane's gate row rr_b = q*16 + w*4 + jw
    const int prow = (q * 16 + w * 4 + jw) * PT_LDS;
#pragma unroll
    for (int mi = 0; mi < 4; ++mi)
#pragma unroll
      for (int r = 0; r < 4; ++r)
        acc[mi][r] += pT[prow + mi * 16 + fq * 4 + r];

    // elementwise, all 64 lanes: lane processes tile mi == q
#pragma unroll
    for (int r = 0; r < 4; ++r) {
      const float y0 = acc[0][r], y1 = acc[1][r], y2 = acc[2][r],
                  y3 = acc[3][r];
      const float f0 = __shfl_xor(y0, 4),  f1 = __shfl_xor(y1, 4),
                  f2 = __shfl_xor(y2, 4),  f3 = __shfl_xor(y3, 4);
      const float g0 = __shfl_xor(y0, 8),  g1 = __shfl_xor(y1, 8),
                  g2 = __shfl_xor(y2, 8),  g3 = __shfl_xor(y3, 8);
      const float o0 = __shfl_xor(y0, 12), o1 = __shfl_xor(y1, 12),
                  o2 = __shfl_xor(y2, 12), o3 = __shfl_xor(y3, 12);
      const float x  = q == 0 ? y0 : q == 1 ? y1 : q == 2 ? y2 : y3;
      const float xf = q == 0 ? f0 : q == 1 ? f1 : q == 2 ? f2 : f3;
      const float xg = q == 0 ? g0 : q == 1 ? g1 : q == 2 ? g2 : g3;
      const float xo = q == 0 ? o0 : q == 1 ? o1 : q == 2 ? o2 : o3;
      // gate permutation by q (x = own gate q; partners at q^1,q^2,q^3)
      const float gi = q == 0 ? x  : q == 1 ? xf : q == 2 ? xg : xo;
      const float gf = q == 0 ? xf : q == 1 ? x  : q == 2 ? xo : xg;
      const float gg = q == 0 ? xg : q == 1 ? xo : q == 2 ? x  : xf;
      const float go = q == 0 ? xo : q == 1 ? xg : q == 2 ? xf : x;
      const float si = sigmoidf_(gi);
      const float sf = sigmoidf_(gf);
      const float tg = tanhf(gg);
      const float so = sigmoidf_(go);
      const float cn = sf * cr[r] + si * tg;
      cr[r] = cn;
      const float hn = so * tanhf(cn);
      const int b = q * 16 + fq * 4 + r;
      hS2[b * 16 + w * 4 + jw] = (f16)hn;
    }
    __syncthreads();

    // coalesced coherent store: block's [64 b][16 u] region in 8B chunks
    {
      f16* slab = hsT + (size_t)t * (64 * 512);
      const int row = tid >> 2;
      const int c4 = tid & 3;
      const f16x4 v = *(const f16x4*)&hS2[row * 16 + c4 * 4];
      store_h4_coh(slab + (size_t)row * 512 + u0 + c4 * 4, v);
    }

    if (t < T_DIM) {
      // prefetch next step's P slice into pT (overlaps barrier wait)
      for (int i = tid; i < 64 * 16; i += 256) {
        const int rr = i >> 4;
        const int q4 = i & 15;
        const int g = rr >> 4, ul = rr & 15;
        const float4 v = *(const float4*)
            &PT[((size_t)(t + 1) * 2048 + g * 512 + u0 + ul) * 64 + q4 * 4];
        *(float4*)&pT[rr * PT_LDS + q4 * 4] = v;
      }
      asm volatile("s_waitcnt vmcnt(0)" ::: "memory");
      __syncthreads();
      if (tid == 0)
        __hip_atomic_store(&flags[blockIdx.x * 16], (unsigned)(t + 1),
                           __ATOMIC_RELAXED, __HIP_MEMORY_SCOPE_AGENT);
      if (tid < NBLK) {
        while (__hip_atomic_load(&flags[tid * 16], __ATOMIC_RELAXED,
                                 __HIP_MEMORY_SCOPE_AGENT) < (unsigned)(t + 1))
          __builtin_amdgcn_s_sleep(3);
      }
      __syncthreads();
    }
  }
}

// ---------------------------------------------------------------------------
// Softmax over V=32000, row in registers (1024 thr).
// ---------------------------------------------------------------------------
__device__ __forceinline__ float waveMax(float v) {
#pragma unroll
  for (int o = 32; o > 0; o >>= 1) v = fmaxf(v, __shfl_down(v, o));
  return v;
}
__device__ __forceinline__ float waveSum(float v) {
#pragma unroll
  for (int o = 32; o > 0; o >>= 1) v += __shfl_down(v, o);
  return v;
}

__global__ __launch_bounds__(1024) void softmax_f16_kernel(
    const f16* __restrict__ lg, float* __restrict__ out) {
  const f16x8* L = (const f16x8*)(lg + (size_t)blockIdx.x * V_DIM);
  float4* p4 = (float4*)(out + (size_t)blockIdx.x * V_DIM);
  const int t = threadIdx.x;
  __shared__ float sred[16];

  float4 v[8];
  float m = -1e30f;
#pragma unroll
  for (int j = 0; j < 4; ++j) {
    const int i = j * 1024 + t;
    if (i < 4000) {
      const f16x8 h = L[i];
      v[2 * j].x     = (float)h[0]; v[2 * j].y     = (float)h[1];
      v[2 * j].z     = (float)h[2]; v[2 * j].w     = (float)h[3];
      v[2 * j + 1].x = (float)h[4]; v[2 * j + 1].y = (float)h[5];
      v[2 * j + 1].z = (float)h[6]; v[2 * j + 1].w = (float)h[7];
      m = fmaxf(m, fmaxf(fmaxf(v[2 * j].x, v[2 * j].y),
                         fmaxf(v[2 * j].z, v[2 * j].w)));
      m = fmaxf(m, fmaxf(fmaxf(v[2 * j + 1].x, v[2 * j + 1].y),
                         fmaxf(v[2 * j + 1].z, v[2 * j + 1].w)));
    }
  }
  m = waveMax(m);
  if ((t & 63) == 0) sred[t >> 6] = m;
  __syncthreads();
  float mb = sred[0];
#pragma unroll
  for (int k = 1; k < 16; ++k) mb = fmaxf(mb, sred[k]);
  __syncthreads();

  float s = 0.f;
#pragma unroll
  for (int j = 0; j < 8; ++j) {
    const int i = (j >> 1) * 1024 + t;
    if (i < 4000) {
      v[j].x = expf(v[j].x - mb);
      v[j].y = expf(v[j].y - mb);
      v[j].z = expf(v[j].z - mb);
      v[j].w = expf(v[j].w - mb);
      s += v[j].x + v[j].y + v[j].z + v[j].w;
    }
  }
  s = waveSum(s);
  if ((t & 63) == 0) sred[t >> 6] = s;
  __syncthreads();
  float sb = sred[0];
#pragma unroll
  for (int k = 1; k < 16; ++k) sb += sred[k];
  const float inv = 1.0f / sb;

#pragma unroll
  for (int j = 0; j < 4; ++j) {
    const int i = j * 1024 + t;
    if (i < 4000) {
      float4 a = v[2 * j], b = v[2 * j + 1];
      a.x *= inv; a.y *= inv; a.z *= inv; a.w *= inv;
      b.x *= inv; b.y *= inv; b.z *= inv; b.w *= inv;
      p4[2 * i] = a;
      p4[2 * i + 1] = b;
    }
  }
}

__global__ __launch_bounds__(1024) void softmax_reg_kernel(
    float* __restrict__ out) {
  float4* p4 = (float4*)(out + (size_t)blockIdx.x * V_DIM);
  const int t = threadIdx.x;
  __shared__ float sred[16];
  float4 v[8];
  float m = -1e30f;
#pragma unroll
  for (int j = 0; j < 8; ++j) {
    const int i = j * 1024 + t;
    if (i < 8000) {
      v[j] = p4[i];
      m = fmaxf(m, fmaxf(fmaxf(v[j].x, v[j].y), fmaxf(v[j].z, v[j].w)));
    }
  }
  m = waveMax(m);
  if ((t & 63) == 0) sred[t >> 6] = m;
  __syncthreads();
  float mb = sred[0];
#pragma unroll
  for (int k = 1; k < 16; ++k) mb = fmaxf(mb, sred[k]);
  __syncthreads();
  float s = 0.f;
#pragma unroll
  for (int j = 0; j < 8; ++j) {
    const int i = j * 1024 + t;
    if (i < 8000) {
      v[j].x = expf(v[j].x - mb);
      v[j].y = expf(v[j].y - mb);
      v[j].z = expf(v[j].z - mb);
      v[j].w = expf(v[j].w - mb);
      s += v[j].x + v[j].y + v[j].z + v[j].w;
    }
  }
  s = waveSum(s);
  if ((t & 63) == 0) sred[t >> 6] = s;
  __syncthreads();
  float sb = sred[0];
#pragma unroll
  for (int k = 1; k < 16; ++k) sb += sred[k];
  const float inv = 1.0f / sb;
#pragma unroll
  for (int j = 0; j < 8; ++j) {
    const int i = j * 1024 + t;
    if (i < 8000) {
      float4 o;
      o.x = v[j].x * inv; o.y = v[j].y * inv;
      o.z = v[j].z * inv; o.w = v[j].w * inv;
      p4[i] = o;
    }
  }
}

// ---------------------------------------------------------------------------
extern "C" void kernel_launch(void* const* d_in, const int* in_sizes, int n_in,
                              void* d_out, int out_size, void* d_ws, size_t ws_size,
                              hipStream_t stream) {
  const float* features = (const float*)d_in[0];
  const int*   captions = (const int*)d_in[1];
  const float* emb      = (const float*)d_in[3];
  const float* w_ih     = (const float*)d_in[4];
  const float* w_hh     = (const float*)d_in[5];
  const float* b_ih     = (const float*)d_in[6];
  const float* b_hh     = (const float*)d_in[7];
  const float* fc_w     = (const float*)d_in[8];
  const float* fc_b     = (const float*)d_in[9];
  float* out = (float*)d_out;

  // ---- d_ws layout ----
  char* ws = (char*)d_ws;
  unsigned* flags = (unsigned*)ws; ws += 2048;                    // 32 x 64B
  f16* hsT = (f16*)ws;  ws += (size_t)21 * B_DIM * H_DIM * 2;     // 1.38 MB
  f16* w16 = (f16*)ws;  ws += (size_t)V_DIM * H_DIM * 2;          // 32.77 MB
  f16* logits16 = (f16*)ws;  // 81.92 MB if available
  const size_t ws_need_f16logits =
      ((char*)logits16 - (char*)d_ws) + (size_t)1280 * V_DIM * 2;  // ~116 MB
  const bool use_f16_logits = ws_size >= ws_need_f16logits;

  // ---- transient scratch in d_out (dead before final output writes) ----
  float* PT    = out;                          // [21][2048][64] f32, 11 MB
  f16*   x16   = (f16*)(out + 3000000);        // [1408][512] f16
  f16*   wih16 = (f16*)(out + 3400000);        // [2048][512] f16
  f16*   whh16 = (f16*)(out + 4000000);        // [2048][512] f16
  float* bsum  = out + 4600000;                // [2048] f32

  hipMemsetAsync(flags, 0, 2048, stream);

  gather_x16_kernel<<<1408, 128, 0, stream>>>(features, captions, emb, x16);
  convert_w_kernel<<<1024, 256, 0, stream>>>(w_ih, wih16);
  convert_w_kernel<<<1024, 256, 0, stream>>>(w_hh, whh16);
  bias_sum_kernel<<<8, 256, 0, stream>>>(b_ih, b_hh, bsum);

  // proj -> P_T[t][gate-row][b]  (mode 2 epilogue)
  gemm16_kernel<<<dim3(16, 11), 256, 0, stream>>>(x16, wih16, bsum, PT, 0, 2);

  // fused: blocks 0..31 = 21 LSTM steps; blocks 32..255 = fc_w convert
  lstm_persistent7<<<NBLK_TOT, 256, 0, stream>>>(PT, whh16, hsT, flags,
                                                 fc_w, w16);

  // FC A = hsT slabs 1..20 (rows t-major), C rows remapped to b-major
  const f16* Afc = hsT + (size_t)B_DIM * H_DIM;
  if (use_f16_logits) {
    gemm16_f16out_kernel<<<dim3(250, 10), 256, 0, stream>>>(Afc, w16, fc_b,
                                                            logits16);
    softmax_f16_kernel<<<1280, 1024, 0, stream>>>(logits16, out);
  } else {
    gemm16_kernel<<<dim3(250, 10), 256, 0, stream>>>(Afc, w16, fc_b, out,
                                                     32000, 1);
    softmax_reg_kernel<<<1280, 1024, 0, stream>>>(out);
  }
}